// Round 6
// baseline (553.354 us; speedup 1.0000x reference)
//
#include <hip/hip_runtime.h>
#include <hip/hip_bf16.h>

#define N_NODES 50000
#define E_EDGES 800000
#define HID 128
#define HEADS 4
#define NEG_SLOPE 0.2f
#define LN_EPS 1e-5f
#define PARAM_FLOATS 17024  // W(16384) al(128) ar(128) b(128) g(128) be(128)

__device__ __forceinline__ float bf2f(__hip_bfloat16 b) { return __bfloat162float(b); }
__device__ __forceinline__ float u2f(unsigned short u) {
    return __uint_as_float(((unsigned int)u) << 16);
}

// ---------- runtime dtype detection (bf16 vs fp32 input buffers) ----------
__global__ __launch_bounds__(256) void detect_kernel(const unsigned int* __restrict__ w0,
                                                     unsigned int* __restrict__ flag) {
    int t = threadIdx.x;
    int cnt = 0;
    for (int i = t; i < 4096; i += 256) {
        unsigned int lo = (w0[i] & 0xFFFFu) << 16;
        float v = fabsf(__uint_as_float(lo));
        if (v >= 1e-6f && v <= 1.0f) cnt++;
    }
    __shared__ int sh[4];
#pragma unroll
    for (int off = 32; off >= 1; off >>= 1) cnt += __shfl_xor(cnt, off);
    if ((t & 63) == 0) sh[t >> 6] = cnt;
    __syncthreads();
    if (t == 0) *flag = ((sh[0] + sh[1] + sh[2] + sh[3]) > 2048) ? 1u : 0u;
}

__device__ __forceinline__ float load_any(const void* p, int i, unsigned int isbf16) {
    return isbf16 ? bf2f(((const __hip_bfloat16*)p)[i]) : ((const float*)p)[i];
}

__global__ __launch_bounds__(256) void cvt_feat_kernel(const void* __restrict__ f,
                                                       const unsigned int* __restrict__ flag,
                                                       float* __restrict__ x, int n) {
    int i = blockIdx.x * 256 + threadIdx.x;
    if (i >= n) return;
    x[i] = load_any(f, i, *flag);
}

__global__ __launch_bounds__(256) void cvt_params_kernel(const void* W, const void* al,
                                                         const void* ar, const void* b,
                                                         const void* g, const void* be,
                                                         const unsigned int* __restrict__ flag,
                                                         float* __restrict__ out) {
    int i = blockIdx.x * 256 + threadIdx.x;
    if (i >= PARAM_FLOATS) return;
    unsigned int isb = *flag;
    const void* src; int off;
    if (i < 16384)      { src = W;  off = i; }
    else if (i < 16512) { src = al; off = i - 16384; }
    else if (i < 16640) { src = ar; off = i - 16512; }
    else if (i < 16768) { src = b;  off = i - 16640; }
    else if (i < 16896) { src = g;  off = i - 16768; }
    else                { src = be; off = i - 16896; }
    out[i] = load_any(src, off, isb);
}

// ---------- CSR build ----------
__global__ __launch_bounds__(256) void hist_kernel(const int* __restrict__ dst,
                                                   int* __restrict__ deg) {
    int i = blockIdx.x * 256 + threadIdx.x;
    if (i < E_EDGES) atomicAdd(&deg[dst[i]], 1);
}

// One block, 1024 threads. Thread t owns deg[t*49 .. t*49+48] (1024*49 = 50176 >= 50001).
__global__ __launch_bounds__(1024) void scan_kernel(const int* __restrict__ deg,
                                                    int* __restrict__ offs) {
    __shared__ int wtot[16];
    __shared__ int woff[16];
    int t = threadIdx.x;
    int lane = t & 63, wid = t >> 6;
    int base = t * 49;

    int tot = 0;
    for (int j = 0; j < 49; ++j) {
        int i = base + j;
        if (i < N_NODES) tot += deg[i];
    }
    // inclusive scan of per-thread totals
    int x = tot;
#pragma unroll
    for (int o = 1; o < 64; o <<= 1) {
        int y = __shfl_up(x, o);
        if (lane >= o) x += y;
    }
    if (lane == 63) wtot[wid] = x;
    __syncthreads();
    if (wid == 0 && lane < 16) {
        int ws = wtot[lane];
        int xs = ws;
#pragma unroll
        for (int o = 1; o < 16; o <<= 1) {
            int y = __shfl_up(xs, o);
            if (lane >= o) xs += y;
        }
        woff[lane] = xs - ws;
    }
    __syncthreads();
    int prefix = woff[wid] + (x - tot);  // exclusive prefix for this thread's chunk
    for (int j = 0; j < 49; ++j) {
        int i = base + j;
        if (i < N_NODES) {
            offs[i] = prefix;
            prefix += deg[i];
        }
    }
    if (t == 1023) offs[N_NODES] = E_EDGES;
}

__global__ __launch_bounds__(256) void scatter_kernel(const int* __restrict__ src,
                                                      const int* __restrict__ dst,
                                                      const int* __restrict__ offs,
                                                      int* __restrict__ cnt,
                                                      int* __restrict__ esrc) {
    int i = blockIdx.x * 256 + threadIdx.x;
    if (i >= E_EDGES) return;
    int d = dst[i];
    int pos = offs[d] + atomicAdd(&cnt[d], 1);
    esrc[pos] = src[i];
}

// ---------- h = x @ W, fp32 register-blocked ----------
__global__ __launch_bounds__(256) void gemm_f32_kernel(const float* __restrict__ x,
                                                       const float* __restrict__ W,
                                                       float* __restrict__ h, int M) {
    __shared__ float xT[16][64];
    __shared__ float wS[16][128];
    int t = threadIdx.x;
    int row0 = blockIdx.x * 64;
    int c0 = (t & 15) * 8;
    int r0 = (t >> 4) * 4;
    int xr = t >> 2;
    int xk = (t & 3) * 4;
    int wr = t >> 4;
    int wc = (t & 15) * 8;

    float acc[4][8];
#pragma unroll
    for (int i = 0; i < 4; i++)
#pragma unroll
        for (int j = 0; j < 8; j++) acc[i][j] = 0.f;

    for (int kc = 0; kc < 8; ++kc) {
        float4 xa = make_float4(0.f, 0.f, 0.f, 0.f);
        int grow = row0 + xr;
        if (grow < M) xa = *(const float4*)(x + grow * 128 + kc * 16 + xk);
        xT[xk + 0][xr] = xa.x; xT[xk + 1][xr] = xa.y;
        xT[xk + 2][xr] = xa.z; xT[xk + 3][xr] = xa.w;
        float4 wa = *(const float4*)(W + (kc * 16 + wr) * 128 + wc);
        float4 wb = *(const float4*)(W + (kc * 16 + wr) * 128 + wc + 4);
        *(float4*)&wS[wr][wc] = wa;
        *(float4*)&wS[wr][wc + 4] = wb;
        __syncthreads();
#pragma unroll
        for (int k = 0; k < 16; ++k) {
            float4 a = *(const float4*)&xT[k][r0];
            float4 b0 = *(const float4*)&wS[k][c0];
            float4 b1 = *(const float4*)&wS[k][c0 + 4];
            float av[4] = {a.x, a.y, a.z, a.w};
            float bv[8] = {b0.x, b0.y, b0.z, b0.w, b1.x, b1.y, b1.z, b1.w};
#pragma unroll
            for (int i = 0; i < 4; i++)
#pragma unroll
                for (int j = 0; j < 8; j++) acc[i][j] = fmaf(av[i], bv[j], acc[i][j]);
        }
        __syncthreads();
    }

#pragma unroll
    for (int i = 0; i < 4; i++) {
        int row = row0 + r0 + i;
        if (row < M) {
            *(float4*)(h + row * 128 + c0)     = make_float4(acc[i][0], acc[i][1], acc[i][2], acc[i][3]);
            *(float4*)(h + row * 128 + c0 + 4) = make_float4(acc[i][4], acc[i][5], acc[i][6], acc[i][7]);
        }
    }
}

// ---------- el/er scores + bf16 message copy ----------
// Reads fp32 h once; emits el/er and hb (bf16 copy of h for the gather in agg).
__global__ __launch_bounds__(256) void scores_kernel(const float* __restrict__ h,
                                                     const float* __restrict__ params,
                                                     float* __restrict__ el,
                                                     float* __restrict__ er,
                                                     unsigned short* __restrict__ hb, int M) {
    int node = (blockIdx.x * 256 + threadIdx.x) >> 6;
    int lane = threadIdx.x & 63;
    if (node >= M) return;
    const float* al = params + 16384;
    const float* ar = params + 16512;
    const float* hr = h + node * 128;
    float h0 = hr[lane], h1 = hr[lane + 64];

    __hip_bfloat16 b0 = __float2bfloat16(h0);
    __hip_bfloat16 b1 = __float2bfloat16(h1);
    hb[node * 128 + lane]      = *(unsigned short*)&b0;
    hb[node * 128 + lane + 64] = *(unsigned short*)&b1;

    float pl0 = h0 * al[lane], pl1 = h1 * al[lane + 64];
    float pr0 = h0 * ar[lane], pr1 = h1 * ar[lane + 64];
#pragma unroll
    for (int off = 16; off >= 1; off >>= 1) {
        pl0 += __shfl_xor(pl0, off);
        pl1 += __shfl_xor(pl1, off);
        pr0 += __shfl_xor(pr0, off);
        pr1 += __shfl_xor(pr1, off);
    }
    if (lane == 0)  { el[node * 4 + 0] = pl0; el[node * 4 + 2] = pl1;
                      er[node * 4 + 0] = pr0; er[node * 4 + 2] = pr1; }
    if (lane == 32) { el[node * 4 + 1] = pl0; el[node * 4 + 3] = pl1;
                      er[node * 4 + 1] = pr0; er[node * 4 + 3] = pr1; }
}

__device__ __forceinline__ float leaky(float v) { return v > 0.f ? v : v * NEG_SLOPE; }

// ---------- fused: two-pass softmax aggregation + bias + LayerNorm + ELU ----------
// One 64-lane wave per dst node; lane owns channels (2*lane, 2*lane+1), head = lane>>4.
// Messages gathered from bf16 hb (4 B/lane).
template <bool LAST>
__global__ __launch_bounds__(256) void agg_ln_kernel(const int* __restrict__ offs,
                                                     const int* __restrict__ esrc,
                                                     const float* __restrict__ el,
                                                     const float* __restrict__ er,
                                                     const unsigned int* __restrict__ hb2,
                                                     const float* __restrict__ params,
                                                     const unsigned int* __restrict__ flag,
                                                     float* __restrict__ x_next,
                                                     void* __restrict__ out) {
    int node = (blockIdx.x * 256 + threadIdx.x) >> 6;
    int lane = threadIdx.x & 63;
    if (node >= N_NODES) return;
    int hd = lane >> 4;
    int c0 = lane * 2;
    float er_d = er[node * 4 + hd];
    int e0 = offs[node], e1 = offs[node + 1];

    // pass 1: max (el is L2-resident; quad-broadcast loads)
    float m = -INFINITY;
    {
        int e = e0;
        for (; e + 1 < e1; e += 2) {
            float va = leaky(el[esrc[e] * 4 + hd] + er_d);
            float vb = leaky(el[esrc[e + 1] * 4 + hd] + er_d);
            m = fmaxf(m, fmaxf(va, vb));
        }
        if (e < e1) m = fmaxf(m, leaky(el[esrc[e] * 4 + hd] + er_d));
    }

    // pass 2: independent iterations, 2-way unrolled
    float l = 0.f, a0 = 0.f, a1 = 0.f;
    {
        int e = e0;
        for (; e + 1 < e1; e += 2) {
            int s0 = esrc[e], s1 = esrc[e + 1];
            float va = leaky(el[s0 * 4 + hd] + er_d);
            float vb = leaky(el[s1 * 4 + hd] + er_d);
            unsigned int p0 = hb2[s0 * 64 + lane];
            unsigned int p1 = hb2[s1 * 64 + lane];
            float ea = __expf(va - m), eb = __expf(vb - m);
            float h0x = u2f((unsigned short)(p0 & 0xFFFFu));
            float h0y = __uint_as_float(p0 & 0xFFFF0000u);
            float h1x = u2f((unsigned short)(p1 & 0xFFFFu));
            float h1y = __uint_as_float(p1 & 0xFFFF0000u);
            l += ea + eb;
            a0 = fmaf(ea, h0x, fmaf(eb, h1x, a0));
            a1 = fmaf(ea, h0y, fmaf(eb, h1y, a1));
        }
        if (e < e1) {
            int s0 = esrc[e];
            float va = leaky(el[s0 * 4 + hd] + er_d);
            unsigned int p0 = hb2[s0 * 64 + lane];
            float ea = __expf(va - m);
            l += ea;
            a0 = fmaf(ea, u2f((unsigned short)(p0 & 0xFFFFu)), a0);
            a1 = fmaf(ea, __uint_as_float(p0 & 0xFFFF0000u), a1);
        }
    }

    float inv = 1.f / fmaxf(l, 1e-9f);
    const float* b  = params + 16640;
    const float* g  = params + 16768;
    const float* be = params + 16896;
    float v0 = fmaf(a0, inv, b[c0]);
    float v1 = fmaf(a1, inv, b[c0 + 1]);

    float s = v0 + v1;
#pragma unroll
    for (int off = 32; off >= 1; off >>= 1) s += __shfl_xor(s, off);
    float mu = s * (1.f / 128.f);
    float q0 = v0 - mu, q1 = v1 - mu;
    float vs = q0 * q0 + q1 * q1;
#pragma unroll
    for (int off = 32; off >= 1; off >>= 1) vs += __shfl_xor(vs, off);
    float rstd = rsqrtf(vs * (1.f / 128.f) + LN_EPS);
    float y0 = q0 * rstd * g[c0] + be[c0];
    float y1 = q1 * rstd * g[c0 + 1] + be[c0 + 1];
    y0 = y0 > 0.f ? y0 : expm1f(y0);
    y1 = y1 > 0.f ? y1 : expm1f(y1);

    if (LAST) {
        if (*flag) {
            __hip_bfloat16 o0 = __float2bfloat16(y0);
            __hip_bfloat16 o1 = __float2bfloat16(y1);
            unsigned int packed = (unsigned int)(*(unsigned short*)&o0)
                                | ((unsigned int)(*(unsigned short*)&o1) << 16);
            ((unsigned int*)out)[node * 64 + lane] = packed;
        } else {
            ((float2*)out)[node * 64 + lane] = make_float2(y0, y1);
        }
    } else {
        ((float2*)x_next)[node * 64 + lane] = make_float2(y0, y1);
    }
}

extern "C" void kernel_launch(void* const* d_in, const int* in_sizes, int n_in,
                              void* d_out, int out_size, void* d_ws, size_t ws_size,
                              hipStream_t stream) {
    const void* features = d_in[0];
    const int* src = (const int*)d_in[1];
    const int* dst = (const int*)d_in[2];

    char* w = (char*)d_ws;
    float* xbuf = (float*)w;                                // 25.6 MB (x / x_next)
    float* hbuf = (float*)(w + 25600000);                   // 25.6 MB (h fp32)
    unsigned short* hb = (unsigned short*)(w + 51200000);   // 12.8 MB (h bf16)
    float* el = (float*)(w + 64000000);                     // 800 KB
    float* er = el + N_NODES * HEADS;                       // 800 KB
    float* params0 = er + N_NODES * HEADS;                  // 68 KB
    float* params1 = params0 + PARAM_FLOATS;                // 68 KB
    int* offs = (int*)(params1 + PARAM_FLOATS);             // 50001
    int* deg  = offs + N_NODES + 1;                         // 50000
    int* esrc = deg + N_NODES;                              // 800000
    unsigned int* flag = (unsigned int*)(esrc + E_EDGES);

    detect_kernel<<<1, 256, 0, stream>>>((const unsigned int*)d_in[3], flag);
    cvt_feat_kernel<<<(N_NODES * HID + 255) / 256, 256, 0, stream>>>(features, flag, xbuf,
                                                                     N_NODES * HID);
    cvt_params_kernel<<<(PARAM_FLOATS + 255) / 256, 256, 0, stream>>>(
        d_in[3], d_in[4], d_in[5], d_in[6], d_in[7], d_in[8], flag, params0);
    cvt_params_kernel<<<(PARAM_FLOATS + 255) / 256, 256, 0, stream>>>(
        d_in[9], d_in[10], d_in[11], d_in[12], d_in[13], d_in[14], flag, params1);

    hipMemsetAsync(deg, 0, N_NODES * sizeof(int), stream);
    hist_kernel<<<(E_EDGES + 255) / 256, 256, 0, stream>>>(dst, deg);
    scan_kernel<<<1, 1024, 0, stream>>>(deg, offs);
    hipMemsetAsync(deg, 0, N_NODES * sizeof(int), stream);
    scatter_kernel<<<(E_EDGES + 255) / 256, 256, 0, stream>>>(src, dst, offs, deg, esrc);

    for (int l = 0; l < 2; ++l) {
        float* params = (l == 0) ? params0 : params1;
        gemm_f32_kernel<<<(N_NODES + 63) / 64, 256, 0, stream>>>(xbuf, params, hbuf, N_NODES);
        scores_kernel<<<(N_NODES * 64 + 255) / 256, 256, 0, stream>>>(hbuf, params, el, er,
                                                                      hb, N_NODES);
        if (l == 0) {
            agg_ln_kernel<false><<<(N_NODES * 64 + 255) / 256, 256, 0, stream>>>(
                offs, esrc, el, er, (const unsigned int*)hb, params, flag, xbuf, nullptr);
        } else {
            agg_ln_kernel<true><<<(N_NODES * 64 + 255) / 256, 256, 0, stream>>>(
                offs, esrc, el, er, (const unsigned int*)hb, params, flag, nullptr, d_out);
        }
    }
}

// Round 7
// 498.874 us; speedup vs baseline: 1.1092x; 1.1092x over previous
//
#include <hip/hip_runtime.h>
#include <hip/hip_bf16.h>

#define N_NODES 50000
#define E_EDGES 800000
#define HID 128
#define HEADS 4
#define NEG_SLOPE 0.2f
#define LN_EPS 1e-5f
#define PARAM_FLOATS 17024  // W(16384) al(128) ar(128) b(128) g(128) be(128)

__device__ __forceinline__ float bf2f(__hip_bfloat16 b) { return __bfloat162float(b); }
__device__ __forceinline__ float u2f(unsigned short u) {
    return __uint_as_float(((unsigned int)u) << 16);
}
__device__ __forceinline__ float leaky(float v) { return v > 0.f ? v : v * NEG_SLOPE; }

// ---------- runtime dtype detection (bf16 vs fp32 input buffers) ----------
__global__ __launch_bounds__(256) void detect_kernel(const unsigned int* __restrict__ w0,
                                                     unsigned int* __restrict__ flag) {
    int t = threadIdx.x;
    int cnt = 0;
    for (int i = t; i < 4096; i += 256) {
        unsigned int lo = (w0[i] & 0xFFFFu) << 16;
        float v = fabsf(__uint_as_float(lo));
        if (v >= 1e-6f && v <= 1.0f) cnt++;
    }
    __shared__ int sh[4];
#pragma unroll
    for (int off = 32; off >= 1; off >>= 1) cnt += __shfl_xor(cnt, off);
    if ((t & 63) == 0) sh[t >> 6] = cnt;
    __syncthreads();
    if (t == 0) *flag = ((sh[0] + sh[1] + sh[2] + sh[3]) > 2048) ? 1u : 0u;
}

__device__ __forceinline__ float load_any(const void* p, int i, unsigned int isbf16) {
    return isbf16 ? bf2f(((const __hip_bfloat16*)p)[i]) : ((const float*)p)[i];
}

__global__ __launch_bounds__(256) void cvt_feat_kernel(const void* __restrict__ f,
                                                       const unsigned int* __restrict__ flag,
                                                       float* __restrict__ x, int n) {
    int i = blockIdx.x * 256 + threadIdx.x;
    if (i >= n) return;
    x[i] = load_any(f, i, *flag);
}

__global__ __launch_bounds__(256) void cvt_params_kernel(const void* W, const void* al,
                                                         const void* ar, const void* b,
                                                         const void* g, const void* be,
                                                         const unsigned int* __restrict__ flag,
                                                         float* __restrict__ out) {
    int i = blockIdx.x * 256 + threadIdx.x;
    if (i >= PARAM_FLOATS) return;
    unsigned int isb = *flag;
    const void* src; int off;
    if (i < 16384)      { src = W;  off = i; }
    else if (i < 16512) { src = al; off = i - 16384; }
    else if (i < 16640) { src = ar; off = i - 16512; }
    else if (i < 16768) { src = b;  off = i - 16640; }
    else if (i < 16896) { src = g;  off = i - 16768; }
    else                { src = be; off = i - 16896; }
    out[i] = load_any(src, off, isb);
}

// ---------- CSR build ----------
__global__ __launch_bounds__(256) void hist_kernel(const int* __restrict__ dst,
                                                   int* __restrict__ deg) {
    int i = blockIdx.x * 256 + threadIdx.x;
    if (i < E_EDGES) atomicAdd(&deg[dst[i]], 1);
}

__global__ __launch_bounds__(1024) void scan_kernel(const int* __restrict__ deg,
                                                    int* __restrict__ offs) {
    __shared__ int wtot[16];
    __shared__ int woff[16];
    int t = threadIdx.x;
    int lane = t & 63, wid = t >> 6;
    int base = t * 49;

    int tot = 0;
    for (int j = 0; j < 49; ++j) {
        int i = base + j;
        if (i < N_NODES) tot += deg[i];
    }
    int x = tot;
#pragma unroll
    for (int o = 1; o < 64; o <<= 1) {
        int y = __shfl_up(x, o);
        if (lane >= o) x += y;
    }
    if (lane == 63) wtot[wid] = x;
    __syncthreads();
    if (wid == 0 && lane < 16) {
        int ws = wtot[lane];
        int xs = ws;
#pragma unroll
        for (int o = 1; o < 16; o <<= 1) {
            int y = __shfl_up(xs, o);
            if (lane >= o) xs += y;
        }
        woff[lane] = xs - ws;
    }
    __syncthreads();
    int prefix = woff[wid] + (x - tot);
    for (int j = 0; j < 49; ++j) {
        int i = base + j;
        if (i < N_NODES) {
            offs[i] = prefix;
            prefix += deg[i];
        }
    }
    if (t == 1023) offs[N_NODES] = E_EDGES;
}

__global__ __launch_bounds__(256) void scatter_kernel(const int* __restrict__ src,
                                                      const int* __restrict__ dst,
                                                      const int* __restrict__ offs,
                                                      int* __restrict__ cnt,
                                                      int* __restrict__ esrc) {
    int i = blockIdx.x * 256 + threadIdx.x;
    if (i >= E_EDGES) return;
    int d = dst[i];
    int pos = offs[d] + atomicAdd(&cnt[d], 1);
    esrc[pos] = src[i];
}

// ---------- fused GEMM: h = x @ W, emits bf16 h + el/er directly ----------
// Block: 256 thr, 64-row tile. Thread: 4 rows x 8 cols (cols within one head).
__global__ __launch_bounds__(256) void gemm_fused_kernel(const float* __restrict__ x,
                                                         const float* __restrict__ params,
                                                         unsigned int* __restrict__ hb2,
                                                         float* __restrict__ el,
                                                         float* __restrict__ er, int M) {
    __shared__ float xT[16][64];
    __shared__ float wS[16][128];
    const float* W = params;
    int t = threadIdx.x;
    int row0 = blockIdx.x * 64;
    int c0 = (t & 15) * 8;
    int r0 = (t >> 4) * 4;
    int xr = t >> 2;
    int xk = (t & 3) * 4;
    int wr = t >> 4;
    int wc = (t & 15) * 8;

    float acc[4][8];
#pragma unroll
    for (int i = 0; i < 4; i++)
#pragma unroll
        for (int j = 0; j < 8; j++) acc[i][j] = 0.f;

    for (int kc = 0; kc < 8; ++kc) {
        float4 xa = make_float4(0.f, 0.f, 0.f, 0.f);
        int grow = row0 + xr;
        if (grow < M) xa = *(const float4*)(x + grow * 128 + kc * 16 + xk);
        xT[xk + 0][xr] = xa.x; xT[xk + 1][xr] = xa.y;
        xT[xk + 2][xr] = xa.z; xT[xk + 3][xr] = xa.w;
        float4 wa = *(const float4*)(W + (kc * 16 + wr) * 128 + wc);
        float4 wb = *(const float4*)(W + (kc * 16 + wr) * 128 + wc + 4);
        *(float4*)&wS[wr][wc] = wa;
        *(float4*)&wS[wr][wc + 4] = wb;
        __syncthreads();
#pragma unroll
        for (int k = 0; k < 16; ++k) {
            float4 a = *(const float4*)&xT[k][r0];
            float4 b0 = *(const float4*)&wS[k][c0];
            float4 b1 = *(const float4*)&wS[k][c0 + 4];
            float av[4] = {a.x, a.y, a.z, a.w};
            float bv[8] = {b0.x, b0.y, b0.z, b0.w, b1.x, b1.y, b1.z, b1.w};
#pragma unroll
            for (int i = 0; i < 4; i++)
#pragma unroll
                for (int j = 0; j < 8; j++) acc[i][j] = fmaf(av[i], bv[j], acc[i][j]);
        }
        __syncthreads();
    }

    // --- epilogue: bf16 h store + el/er dots ---
    int lane = t & 63;
    float al8[8], ar8[8];
#pragma unroll
    for (int j = 0; j < 8; j++) {
        al8[j] = params[16384 + c0 + j];
        ar8[j] = params[16512 + c0 + j];
    }
    int head = (lane & 15) >> 2;   // head of this thread's 8 cols

#pragma unroll
    for (int i = 0; i < 4; i++) {
        int row = row0 + r0 + i;
        bool ok = row < M;
        if (ok) {
            unsigned int u[4];
#pragma unroll
            for (int j = 0; j < 4; j++) {
                __hip_bfloat16 p0 = __float2bfloat16(acc[i][2 * j]);
                __hip_bfloat16 p1 = __float2bfloat16(acc[i][2 * j + 1]);
                u[j] = (unsigned int)(*(unsigned short*)&p0)
                     | ((unsigned int)(*(unsigned short*)&p1) << 16);
            }
            *(uint4*)(hb2 + row * 64 + (c0 >> 1)) = make_uint4(u[0], u[1], u[2], u[3]);
        }
        float e_l = 0.f, e_r = 0.f;
#pragma unroll
        for (int j = 0; j < 8; j++) {
            e_l = fmaf(acc[i][j], al8[j], e_l);
            e_r = fmaf(acc[i][j], ar8[j], e_r);
        }
        e_l += __shfl_xor(e_l, 1); e_l += __shfl_xor(e_l, 2);
        e_r += __shfl_xor(e_r, 1); e_r += __shfl_xor(e_r, 2);
        if (ok && (lane & 3) == 0) {
            el[row * 4 + head] = e_l;
            er[row * 4 + head] = e_r;
        }
    }
}

// ---------- fused: batched-score softmax aggregation + bias + LayerNorm + ELU ----------
// One wave per dst node. Scoring: lane = slot*4 + head (16 edges x 4 heads per batch).
// Channels: lane owns (2*lane, 2*lane+1), head hd = lane>>4.
template <bool LAST>
__global__ __launch_bounds__(256) void agg_ln_kernel(const int* __restrict__ offs,
                                                     const int* __restrict__ esrc,
                                                     const float* __restrict__ el,
                                                     const float* __restrict__ er,
                                                     const unsigned int* __restrict__ hb2,
                                                     const float* __restrict__ params,
                                                     const unsigned int* __restrict__ flag,
                                                     float* __restrict__ x_next,
                                                     void* __restrict__ out) {
    int node = (blockIdx.x * 256 + threadIdx.x) >> 6;
    int lane = threadIdx.x & 63;
    if (node >= N_NODES) return;
    int e0 = offs[node], e1 = offs[node + 1];
    int d = e1 - e0;
    int sh = lane & 3;        // scoring head
    int slot = lane >> 2;     // edge slot in batch (0..15)
    float er_s = er[node * 4 + sh];

    // sweep 1: per-head max, 16 edges per wave-step
    float vmax = -INFINITY;
    for (int b0 = 0; b0 < d; b0 += 16) {
        int idx = b0 + slot;
        if (idx < d) {
            int s = esrc[e0 + idx];
            vmax = fmaxf(vmax, leaky(el[s * 4 + sh] + er_s));
        }
    }
#pragma unroll
    for (int off = 4; off <= 32; off <<= 1) vmax = fmaxf(vmax, __shfl_xor(vmax, off));
    float m = vmax;  // per lane: max for head sh

    int hd = lane >> 4;       // channel head
    int c0 = lane * 2;

    // sweep 2: exp + denom partials + channel accumulation
    float lsum = 0.f, a0 = 0.f, a1 = 0.f;
    for (int b0 = 0; b0 < d; b0 += 16) {
        int idx = b0 + slot;
        float ex = 0.f;
        int s = 0;
        if (idx < d) {
            s = esrc[e0 + idx];
            ex = __expf(leaky(el[s * 4 + sh] + er_s) - m);
        }
        lsum += ex;
        int nb = min(16, d - b0);
        for (int j = 0; j < nb; ++j) {
            int sj = __shfl(s, j * 4);
            float exj = __shfl(ex, j * 4 + hd);
            unsigned int p = hb2[sj * 64 + lane];
            a0 = fmaf(exj, u2f((unsigned short)(p & 0xFFFFu)), a0);
            a1 = fmaf(exj, __uint_as_float(p & 0xFFFF0000u), a1);
        }
    }
#pragma unroll
    for (int off = 4; off <= 32; off <<= 1) lsum += __shfl_xor(lsum, off);
    float l = __shfl(lsum, hd);   // denom for this lane's channel head

    float inv = 1.f / fmaxf(l, 1e-9f);
    const float* b  = params + 16640;
    const float* g  = params + 16768;
    const float* be = params + 16896;
    float v0 = fmaf(a0, inv, b[c0]);
    float v1 = fmaf(a1, inv, b[c0 + 1]);

    float s = v0 + v1;
#pragma unroll
    for (int off = 32; off >= 1; off >>= 1) s += __shfl_xor(s, off);
    float mu = s * (1.f / 128.f);
    float q0 = v0 - mu, q1 = v1 - mu;
    float vs = q0 * q0 + q1 * q1;
#pragma unroll
    for (int off = 32; off >= 1; off >>= 1) vs += __shfl_xor(vs, off);
    float rstd = rsqrtf(vs * (1.f / 128.f) + LN_EPS);
    float y0 = q0 * rstd * g[c0] + be[c0];
    float y1 = q1 * rstd * g[c0 + 1] + be[c0 + 1];
    y0 = y0 > 0.f ? y0 : expm1f(y0);
    y1 = y1 > 0.f ? y1 : expm1f(y1);

    if (LAST) {
        if (*flag) {
            __hip_bfloat16 o0 = __float2bfloat16(y0);
            __hip_bfloat16 o1 = __float2bfloat16(y1);
            unsigned int packed = (unsigned int)(*(unsigned short*)&o0)
                                | ((unsigned int)(*(unsigned short*)&o1) << 16);
            ((unsigned int*)out)[node * 64 + lane] = packed;
        } else {
            ((float2*)out)[node * 64 + lane] = make_float2(y0, y1);
        }
    } else {
        ((float2*)x_next)[node * 64 + lane] = make_float2(y0, y1);
    }
}

extern "C" void kernel_launch(void* const* d_in, const int* in_sizes, int n_in,
                              void* d_out, int out_size, void* d_ws, size_t ws_size,
                              hipStream_t stream) {
    const void* features = d_in[0];
    const int* src = (const int*)d_in[1];
    const int* dst = (const int*)d_in[2];

    char* w = (char*)d_ws;
    float* xbuf = (float*)w;                               // 25.6 MB (x / x_next)
    unsigned int* hb = (unsigned int*)(w + 25600000);      // 12.8 MB (h bf16 packed)
    float* el = (float*)(w + 38400000);                    // 800 KB
    float* er = (float*)(w + 39200000);                    // 800 KB
    float* params0 = (float*)(w + 40000000);               // 68 KB
    float* params1 = params0 + PARAM_FLOATS;               // 68 KB
    int* offs = (int*)(w + 40137000);                      // 50001 ints
    int* deg  = (int*)(w + 40338000);                      // 50000 ints
    int* esrc = (int*)(w + 40539000);                      // 800000 ints
    unsigned int* flag = (unsigned int*)(w + 43739000);

    detect_kernel<<<1, 256, 0, stream>>>((const unsigned int*)d_in[3], flag);
    cvt_feat_kernel<<<(N_NODES * HID + 255) / 256, 256, 0, stream>>>(features, flag, xbuf,
                                                                     N_NODES * HID);
    cvt_params_kernel<<<(PARAM_FLOATS + 255) / 256, 256, 0, stream>>>(
        d_in[3], d_in[4], d_in[5], d_in[6], d_in[7], d_in[8], flag, params0);
    cvt_params_kernel<<<(PARAM_FLOATS + 255) / 256, 256, 0, stream>>>(
        d_in[9], d_in[10], d_in[11], d_in[12], d_in[13], d_in[14], flag, params1);

    hipMemsetAsync(deg, 0, N_NODES * sizeof(int), stream);
    hist_kernel<<<(E_EDGES + 255) / 256, 256, 0, stream>>>(dst, deg);
    scan_kernel<<<1, 1024, 0, stream>>>(deg, offs);
    hipMemsetAsync(deg, 0, N_NODES * sizeof(int), stream);
    scatter_kernel<<<(E_EDGES + 255) / 256, 256, 0, stream>>>(src, dst, offs, deg, esrc);

    for (int l = 0; l < 2; ++l) {
        float* params = (l == 0) ? params0 : params1;
        gemm_fused_kernel<<<(N_NODES + 63) / 64, 256, 0, stream>>>(xbuf, params, hb, el, er,
                                                                   N_NODES);
        if (l == 0) {
            agg_ln_kernel<false><<<(N_NODES * 64 + 255) / 256, 256, 0, stream>>>(
                offs, esrc, el, er, hb, params, flag, xbuf, nullptr);
        } else {
            agg_ln_kernel<true><<<(N_NODES * 64 + 255) / 256, 256, 0, stream>>>(
                offs, esrc, el, er, hb, params, flag, nullptr, d_out);
        }
    }
}

// Round 8
// 414.306 us; speedup vs baseline: 1.3356x; 1.2041x over previous
//
#include <hip/hip_runtime.h>
#include <hip/hip_bf16.h>

#define N_NODES 50000
#define E_EDGES 800000
#define HID 128
#define HEADS 4
#define NEG_SLOPE 0.2f
#define LN_EPS 1e-5f
#define PARAM_FLOATS 17024  // W(16384) al(128) ar(128) b(128) g(128) be(128)
#define SCAN_BLOCKS ((N_NODES + 255) / 256)  // 196

__device__ __forceinline__ float bf2f(__hip_bfloat16 b) { return __bfloat162float(b); }
__device__ __forceinline__ float u2f(unsigned short u) {
    return __uint_as_float(((unsigned int)u) << 16);
}
__device__ __forceinline__ float leaky(float v) { return v > 0.f ? v : v * NEG_SLOPE; }

// ---------- runtime dtype detection (bf16 vs fp32 input buffers) ----------
__global__ __launch_bounds__(256) void detect_kernel(const unsigned int* __restrict__ w0,
                                                     unsigned int* __restrict__ flag) {
    int t = threadIdx.x;
    int cnt = 0;
    for (int i = t; i < 4096; i += 256) {
        unsigned int lo = (w0[i] & 0xFFFFu) << 16;
        float v = fabsf(__uint_as_float(lo));
        if (v >= 1e-6f && v <= 1.0f) cnt++;
    }
    __shared__ int sh[4];
#pragma unroll
    for (int off = 32; off >= 1; off >>= 1) cnt += __shfl_xor(cnt, off);
    if ((t & 63) == 0) sh[t >> 6] = cnt;
    __syncthreads();
    if (t == 0) *flag = ((sh[0] + sh[1] + sh[2] + sh[3]) > 2048) ? 1u : 0u;
}

__device__ __forceinline__ float load_any(const void* p, int i, unsigned int isbf16) {
    return isbf16 ? bf2f(((const __hip_bfloat16*)p)[i]) : ((const float*)p)[i];
}

__global__ __launch_bounds__(256) void cvt_feat_kernel(const void* __restrict__ f,
                                                       const unsigned int* __restrict__ flag,
                                                       float* __restrict__ x, int n) {
    int i = blockIdx.x * 256 + threadIdx.x;
    if (i >= n) return;
    x[i] = load_any(f, i, *flag);
}

__global__ __launch_bounds__(256) void cvt_params_kernel(const void* W, const void* al,
                                                         const void* ar, const void* b,
                                                         const void* g, const void* be,
                                                         const unsigned int* __restrict__ flag,
                                                         float* __restrict__ out) {
    int i = blockIdx.x * 256 + threadIdx.x;
    if (i >= PARAM_FLOATS) return;
    unsigned int isb = *flag;
    const void* src; int off;
    if (i < 16384)      { src = W;  off = i; }
    else if (i < 16512) { src = al; off = i - 16384; }
    else if (i < 16640) { src = ar; off = i - 16512; }
    else if (i < 16768) { src = b;  off = i - 16640; }
    else if (i < 16896) { src = g;  off = i - 16768; }
    else                { src = be; off = i - 16896; }
    out[i] = load_any(src, off, isb);
}

// ---------- CSR build ----------
__global__ __launch_bounds__(256) void hist_kernel(const int* __restrict__ dst,
                                                   int* __restrict__ deg) {
    int i = blockIdx.x * 256 + threadIdx.x;
    if (i < E_EDGES) atomicAdd(&deg[dst[i]], 1);
}

// Phase A: per-block (256-elem) sums, coalesced.
__global__ __launch_bounds__(256) void scan_reduce_kernel(const int* __restrict__ deg,
                                                          int* __restrict__ bsum) {
    int i = blockIdx.x * 256 + threadIdx.x;
    int v = (i < N_NODES) ? deg[i] : 0;
#pragma unroll
    for (int o = 32; o >= 1; o >>= 1) v += __shfl_xor(v, o);
    __shared__ int ws[4];
    if ((threadIdx.x & 63) == 0) ws[threadIdx.x >> 6] = v;
    __syncthreads();
    if (threadIdx.x == 0) bsum[blockIdx.x] = ws[0] + ws[1] + ws[2] + ws[3];
}

// Phase B: exclusive scan of the SCAN_BLOCKS block sums (single block, in place).
__global__ __launch_bounds__(256) void scan_bsum_kernel(int* __restrict__ bsum) {
    int t = threadIdx.x;
    int lane = t & 63, wid = t >> 6;
    int v = (t < SCAN_BLOCKS) ? bsum[t] : 0;
    int x = v;
#pragma unroll
    for (int o = 1; o < 64; o <<= 1) {
        int y = __shfl_up(x, o);
        if (lane >= o) x += y;
    }
    __shared__ int wt[4];
    if (lane == 63) wt[wid] = x;
    __syncthreads();
    int add = 0;
    for (int j = 0; j < wid; j++) add += wt[j];
    if (t < SCAN_BLOCKS) bsum[t] = x - v + add;  // exclusive
}

// Phase C: block-local exclusive scan + block offset, coalesced write of offs.
__global__ __launch_bounds__(256) void scan_write_kernel(const int* __restrict__ deg,
                                                         const int* __restrict__ bsum,
                                                         int* __restrict__ offs) {
    int t = threadIdx.x;
    int i = blockIdx.x * 256 + t;
    int lane = t & 63, wid = t >> 6;
    int v = (i < N_NODES) ? deg[i] : 0;
    int x = v;
#pragma unroll
    for (int o = 1; o < 64; o <<= 1) {
        int y = __shfl_up(x, o);
        if (lane >= o) x += y;
    }
    __shared__ int wt[4];
    if (lane == 63) wt[wid] = x;
    __syncthreads();
    int add = bsum[blockIdx.x];
    for (int j = 0; j < wid; j++) add += wt[j];
    if (i < N_NODES) offs[i] = add + x - v;
    if (i == N_NODES) offs[N_NODES] = E_EDGES;
}

__global__ __launch_bounds__(256) void scatter_kernel(const int* __restrict__ src,
                                                      const int* __restrict__ dst,
                                                      const int* __restrict__ offs,
                                                      int* __restrict__ cnt,
                                                      int* __restrict__ esrc) {
    int i = blockIdx.x * 256 + threadIdx.x;
    if (i >= E_EDGES) return;
    int d = dst[i];
    int pos = offs[d] + atomicAdd(&cnt[d], 1);
    esrc[pos] = src[i];
}

// ---------- fused GEMM: h = x @ W, emits bf16 h + el/er directly ----------
__global__ __launch_bounds__(256) void gemm_fused_kernel(const float* __restrict__ x,
                                                         const float* __restrict__ params,
                                                         unsigned int* __restrict__ hb2,
                                                         float* __restrict__ el,
                                                         float* __restrict__ er, int M) {
    __shared__ float xT[16][64];
    __shared__ float wS[16][128];
    const float* W = params;
    int t = threadIdx.x;
    int row0 = blockIdx.x * 64;
    int c0 = (t & 15) * 8;
    int r0 = (t >> 4) * 4;
    int xr = t >> 2;
    int xk = (t & 3) * 4;
    int wr = t >> 4;
    int wc = (t & 15) * 8;

    float acc[4][8];
#pragma unroll
    for (int i = 0; i < 4; i++)
#pragma unroll
        for (int j = 0; j < 8; j++) acc[i][j] = 0.f;

    for (int kc = 0; kc < 8; ++kc) {
        float4 xa = make_float4(0.f, 0.f, 0.f, 0.f);
        int grow = row0 + xr;
        if (grow < M) xa = *(const float4*)(x + grow * 128 + kc * 16 + xk);
        xT[xk + 0][xr] = xa.x; xT[xk + 1][xr] = xa.y;
        xT[xk + 2][xr] = xa.z; xT[xk + 3][xr] = xa.w;
        float4 wa = *(const float4*)(W + (kc * 16 + wr) * 128 + wc);
        float4 wb = *(const float4*)(W + (kc * 16 + wr) * 128 + wc + 4);
        *(float4*)&wS[wr][wc] = wa;
        *(float4*)&wS[wr][wc + 4] = wb;
        __syncthreads();
#pragma unroll
        for (int k = 0; k < 16; ++k) {
            float4 a = *(const float4*)&xT[k][r0];
            float4 b0 = *(const float4*)&wS[k][c0];
            float4 b1 = *(const float4*)&wS[k][c0 + 4];
            float av[4] = {a.x, a.y, a.z, a.w};
            float bv[8] = {b0.x, b0.y, b0.z, b0.w, b1.x, b1.y, b1.z, b1.w};
#pragma unroll
            for (int i = 0; i < 4; i++)
#pragma unroll
                for (int j = 0; j < 8; j++) acc[i][j] = fmaf(av[i], bv[j], acc[i][j]);
        }
        __syncthreads();
    }

    // --- epilogue: bf16 h store + el/er dots ---
    int lane = t & 63;
    float al8[8], ar8[8];
#pragma unroll
    for (int j = 0; j < 8; j++) {
        al8[j] = params[16384 + c0 + j];
        ar8[j] = params[16512 + c0 + j];
    }
    int head = (lane & 15) >> 2;

#pragma unroll
    for (int i = 0; i < 4; i++) {
        int row = row0 + r0 + i;
        bool ok = row < M;
        if (ok) {
            unsigned int u[4];
#pragma unroll
            for (int j = 0; j < 4; j++) {
                __hip_bfloat16 p0 = __float2bfloat16(acc[i][2 * j]);
                __hip_bfloat16 p1 = __float2bfloat16(acc[i][2 * j + 1]);
                u[j] = (unsigned int)(*(unsigned short*)&p0)
                     | ((unsigned int)(*(unsigned short*)&p1) << 16);
            }
            *(uint4*)(hb2 + row * 64 + (c0 >> 1)) = make_uint4(u[0], u[1], u[2], u[3]);
        }
        float e_l = 0.f, e_r = 0.f;
#pragma unroll
        for (int j = 0; j < 8; j++) {
            e_l = fmaf(acc[i][j], al8[j], e_l);
            e_r = fmaf(acc[i][j], ar8[j], e_r);
        }
        e_l += __shfl_xor(e_l, 1); e_l += __shfl_xor(e_l, 2);
        e_r += __shfl_xor(e_r, 1); e_r += __shfl_xor(e_r, 2);
        if (ok && (lane & 3) == 0) {
            el[row * 4 + head] = e_l;
            er[row * 4 + head] = e_r;
        }
    }
}

// ---------- fused: batched-score softmax aggregation + bias + LayerNorm + ELU ----------
template <bool LAST>
__global__ __launch_bounds__(256) void agg_ln_kernel(const int* __restrict__ offs,
                                                     const int* __restrict__ esrc,
                                                     const float* __restrict__ el,
                                                     const float* __restrict__ er,
                                                     const unsigned int* __restrict__ hb2,
                                                     const float* __restrict__ params,
                                                     const unsigned int* __restrict__ flag,
                                                     float* __restrict__ x_next,
                                                     void* __restrict__ out) {
    int node = (blockIdx.x * 256 + threadIdx.x) >> 6;
    int lane = threadIdx.x & 63;
    if (node >= N_NODES) return;
    int e0 = offs[node], e1 = offs[node + 1];
    int d = e1 - e0;
    int sh = lane & 3;
    int slot = lane >> 2;
    float er_s = er[node * 4 + sh];

    float vmax = -INFINITY;
    for (int b0 = 0; b0 < d; b0 += 16) {
        int idx = b0 + slot;
        if (idx < d) {
            int s = esrc[e0 + idx];
            vmax = fmaxf(vmax, leaky(el[s * 4 + sh] + er_s));
        }
    }
#pragma unroll
    for (int off = 4; off <= 32; off <<= 1) vmax = fmaxf(vmax, __shfl_xor(vmax, off));
    float m = vmax;

    int hd = lane >> 4;
    int c0 = lane * 2;

    float lsum = 0.f, a0 = 0.f, a1 = 0.f;
    for (int b0 = 0; b0 < d; b0 += 16) {
        int idx = b0 + slot;
        float ex = 0.f;
        int s = 0;
        if (idx < d) {
            s = esrc[e0 + idx];
            ex = __expf(leaky(el[s * 4 + sh] + er_s) - m);
        }
        lsum += ex;
        int nb = min(16, d - b0);
        for (int j = 0; j < nb; ++j) {
            int sj = __shfl(s, j * 4);
            float exj = __shfl(ex, j * 4 + hd);
            unsigned int p = hb2[sj * 64 + lane];
            a0 = fmaf(exj, u2f((unsigned short)(p & 0xFFFFu)), a0);
            a1 = fmaf(exj, __uint_as_float(p & 0xFFFF0000u), a1);
        }
    }
#pragma unroll
    for (int off = 4; off <= 32; off <<= 1) lsum += __shfl_xor(lsum, off);
    float l = __shfl(lsum, hd);

    float inv = 1.f / fmaxf(l, 1e-9f);
    const float* b  = params + 16640;
    const float* g  = params + 16768;
    const float* be = params + 16896;
    float v0 = fmaf(a0, inv, b[c0]);
    float v1 = fmaf(a1, inv, b[c0 + 1]);

    float s = v0 + v1;
#pragma unroll
    for (int off = 32; off >= 1; off >>= 1) s += __shfl_xor(s, off);
    float mu = s * (1.f / 128.f);
    float q0 = v0 - mu, q1 = v1 - mu;
    float vs = q0 * q0 + q1 * q1;
#pragma unroll
    for (int off = 32; off >= 1; off >>= 1) vs += __shfl_xor(vs, off);
    float rstd = rsqrtf(vs * (1.f / 128.f) + LN_EPS);
    float y0 = q0 * rstd * g[c0] + be[c0];
    float y1 = q1 * rstd * g[c0 + 1] + be[c0 + 1];
    y0 = y0 > 0.f ? y0 : expm1f(y0);
    y1 = y1 > 0.f ? y1 : expm1f(y1);

    if (LAST) {
        if (*flag) {
            __hip_bfloat16 o0 = __float2bfloat16(y0);
            __hip_bfloat16 o1 = __float2bfloat16(y1);
            unsigned int packed = (unsigned int)(*(unsigned short*)&o0)
                                | ((unsigned int)(*(unsigned short*)&o1) << 16);
            ((unsigned int*)out)[node * 64 + lane] = packed;
        } else {
            ((float2*)out)[node * 64 + lane] = make_float2(y0, y1);
        }
    } else {
        ((float2*)x_next)[node * 64 + lane] = make_float2(y0, y1);
    }
}

extern "C" void kernel_launch(void* const* d_in, const int* in_sizes, int n_in,
                              void* d_out, int out_size, void* d_ws, size_t ws_size,
                              hipStream_t stream) {
    const void* features = d_in[0];
    const int* src = (const int*)d_in[1];
    const int* dst = (const int*)d_in[2];

    char* w = (char*)d_ws;
    float* xbuf = (float*)w;                               // 25.6 MB (x / x_next)
    unsigned int* hb = (unsigned int*)(w + 25600000);      // 12.8 MB (h bf16 packed)
    float* el = (float*)(w + 38400000);                    // 800 KB
    float* er = (float*)(w + 39200000);                    // 800 KB
    float* params0 = (float*)(w + 40000000);               // 68 KB
    float* params1 = params0 + PARAM_FLOATS;               // 68 KB
    int* offs = (int*)(w + 40137000);                      // 50001 ints
    int* deg  = (int*)(w + 40338000);                      // 50000 ints
    int* esrc = (int*)(w + 40539000);                      // 800000 ints
    int* bsum = (int*)(w + 43739008);                      // 196 ints
    unsigned int* flag = (unsigned int*)(w + 43740032);

    detect_kernel<<<1, 256, 0, stream>>>((const unsigned int*)d_in[3], flag);
    cvt_feat_kernel<<<(N_NODES * HID + 255) / 256, 256, 0, stream>>>(features, flag, xbuf,
                                                                     N_NODES * HID);
    cvt_params_kernel<<<(PARAM_FLOATS + 255) / 256, 256, 0, stream>>>(
        d_in[3], d_in[4], d_in[5], d_in[6], d_in[7], d_in[8], flag, params0);
    cvt_params_kernel<<<(PARAM_FLOATS + 255) / 256, 256, 0, stream>>>(
        d_in[9], d_in[10], d_in[11], d_in[12], d_in[13], d_in[14], flag, params1);

    hipMemsetAsync(deg, 0, N_NODES * sizeof(int), stream);
    hist_kernel<<<(E_EDGES + 255) / 256, 256, 0, stream>>>(dst, deg);
    scan_reduce_kernel<<<SCAN_BLOCKS, 256, 0, stream>>>(deg, bsum);
    scan_bsum_kernel<<<1, 256, 0, stream>>>(bsum);
    scan_write_kernel<<<SCAN_BLOCKS, 256, 0, stream>>>(deg, bsum, offs);
    hipMemsetAsync(deg, 0, N_NODES * sizeof(int), stream);
    scatter_kernel<<<(E_EDGES + 255) / 256, 256, 0, stream>>>(src, dst, offs, deg, esrc);

    for (int l = 0; l < 2; ++l) {
        float* params = (l == 0) ? params0 : params1;
        gemm_fused_kernel<<<(N_NODES + 63) / 64, 256, 0, stream>>>(xbuf, params, hb, el, er,
                                                                   N_NODES);
        if (l == 0) {
            agg_ln_kernel<false><<<(N_NODES * 64 + 255) / 256, 256, 0, stream>>>(
                offs, esrc, el, er, hb, params, flag, xbuf, nullptr);
        } else {
            agg_ln_kernel<true><<<(N_NODES * 64 + 255) / 256, 256, 0, stream>>>(
                offs, esrc, el, er, hb, params, flag, nullptr, d_out);
        }
    }
}

// Round 9
// 360.831 us; speedup vs baseline: 1.5336x; 1.1482x over previous
//
#include <hip/hip_runtime.h>
#include <hip/hip_bf16.h>

#define N_NODES 50000
#define E_EDGES 800000
#define HID 128
#define HEADS 4
#define NEG_SLOPE 0.2f
#define LN_EPS 1e-5f
#define PARAM_FLOATS 17024  // W(16384) al(128) ar(128) b(128) g(128) be(128)
#define SCAN_BLOCKS ((N_NODES + 255) / 256)  // 196

__device__ __forceinline__ float bf2f(__hip_bfloat16 b) { return __bfloat162float(b); }
__device__ __forceinline__ float u2f(unsigned short u) {
    return __uint_as_float(((unsigned int)u) << 16);
}
__device__ __forceinline__ float leaky(float v) { return v > 0.f ? v : v * NEG_SLOPE; }

// order-preserving float<->uint for atomicMax over signed floats
__device__ __forceinline__ unsigned int f2ord(float f) {
    unsigned int u = __float_as_uint(f);
    return (u & 0x80000000u) ? ~u : (u | 0x80000000u);
}
__device__ __forceinline__ float ord2f(unsigned int u) {
    u = (u & 0x80000000u) ? (u & 0x7FFFFFFFu) : ~u;
    return __uint_as_float(u);
}

// ---------- runtime dtype detection + gmax init ----------
__global__ __launch_bounds__(256) void detect_kernel(const unsigned int* __restrict__ w0,
                                                     unsigned int* __restrict__ flag,
                                                     unsigned int* __restrict__ gmax0,
                                                     unsigned int* __restrict__ gmax1) {
    int t = threadIdx.x;
    if (t < 4) {
        gmax0[t] = f2ord(-INFINITY);
        gmax1[t] = f2ord(-INFINITY);
    }
    int cnt = 0;
    for (int i = t; i < 4096; i += 256) {
        unsigned int lo = (w0[i] & 0xFFFFu) << 16;
        float v = fabsf(__uint_as_float(lo));
        if (v >= 1e-6f && v <= 1.0f) cnt++;
    }
    __shared__ int sh[4];
#pragma unroll
    for (int off = 32; off >= 1; off >>= 1) cnt += __shfl_xor(cnt, off);
    if ((t & 63) == 0) sh[t >> 6] = cnt;
    __syncthreads();
    if (t == 0) *flag = ((sh[0] + sh[1] + sh[2] + sh[3]) > 2048) ? 1u : 0u;
}

__device__ __forceinline__ float load_any(const void* p, int i, unsigned int isbf16) {
    return isbf16 ? bf2f(((const __hip_bfloat16*)p)[i]) : ((const float*)p)[i];
}

__global__ __launch_bounds__(256) void cvt_params_kernel(const void* W, const void* al,
                                                         const void* ar, const void* b,
                                                         const void* g, const void* be,
                                                         const unsigned int* __restrict__ flag,
                                                         float* __restrict__ out) {
    int i = blockIdx.x * 256 + threadIdx.x;
    if (i >= PARAM_FLOATS) return;
    unsigned int isb = *flag;
    const void* src; int off;
    if (i < 16384)      { src = W;  off = i; }
    else if (i < 16512) { src = al; off = i - 16384; }
    else if (i < 16640) { src = ar; off = i - 16512; }
    else if (i < 16768) { src = b;  off = i - 16640; }
    else if (i < 16896) { src = g;  off = i - 16768; }
    else                { src = be; off = i - 16896; }
    out[i] = load_any(src, off, isb);
}

// ---------- CSR build ----------
__global__ __launch_bounds__(256) void hist_kernel(const int* __restrict__ dst,
                                                   int* __restrict__ deg) {
    int i = blockIdx.x * 256 + threadIdx.x;
    if (i < E_EDGES) atomicAdd(&deg[dst[i]], 1);
}

__global__ __launch_bounds__(256) void scan_reduce_kernel(const int* __restrict__ deg,
                                                          int* __restrict__ bsum) {
    int i = blockIdx.x * 256 + threadIdx.x;
    int v = (i < N_NODES) ? deg[i] : 0;
#pragma unroll
    for (int o = 32; o >= 1; o >>= 1) v += __shfl_xor(v, o);
    __shared__ int ws[4];
    if ((threadIdx.x & 63) == 0) ws[threadIdx.x >> 6] = v;
    __syncthreads();
    if (threadIdx.x == 0) bsum[blockIdx.x] = ws[0] + ws[1] + ws[2] + ws[3];
}

__global__ __launch_bounds__(256) void scan_bsum_kernel(int* __restrict__ bsum) {
    int t = threadIdx.x;
    int lane = t & 63, wid = t >> 6;
    int v = (t < SCAN_BLOCKS) ? bsum[t] : 0;
    int x = v;
#pragma unroll
    for (int o = 1; o < 64; o <<= 1) {
        int y = __shfl_up(x, o);
        if (lane >= o) x += y;
    }
    __shared__ int wt[4];
    if (lane == 63) wt[wid] = x;
    __syncthreads();
    int add = 0;
    for (int j = 0; j < wid; j++) add += wt[j];
    if (t < SCAN_BLOCKS) bsum[t] = x - v + add;  // exclusive
}

__global__ __launch_bounds__(256) void scan_write_kernel(const int* __restrict__ deg,
                                                         const int* __restrict__ bsum,
                                                         int* __restrict__ offs) {
    int t = threadIdx.x;
    int i = blockIdx.x * 256 + t;
    int lane = t & 63, wid = t >> 6;
    int v = (i < N_NODES) ? deg[i] : 0;
    int x = v;
#pragma unroll
    for (int o = 1; o < 64; o <<= 1) {
        int y = __shfl_up(x, o);
        if (lane >= o) x += y;
    }
    __shared__ int wt[4];
    if (lane == 63) wt[wid] = x;
    __syncthreads();
    int add = bsum[blockIdx.x];
    for (int j = 0; j < wid; j++) add += wt[j];
    if (i < N_NODES) offs[i] = add + x - v;
    if (i == N_NODES) offs[N_NODES] = E_EDGES;
}

__global__ __launch_bounds__(256) void scatter_kernel(const int* __restrict__ src,
                                                      const int* __restrict__ dst,
                                                      const int* __restrict__ offs,
                                                      int* __restrict__ cnt,
                                                      int* __restrict__ esrc) {
    int i = blockIdx.x * 256 + threadIdx.x;
    if (i >= E_EDGES) return;
    int d = dst[i];
    int pos = offs[d] + atomicAdd(&cnt[d], 1);
    esrc[pos] = src[i];
}

// ---------- fused GEMM: h = x @ W -> bf16 h, el/er, per-head global el-max ----------
// Block: 256 thr, 64-row tile. Thread: 4 rows x 8 cols (cols within one head).
// xsel: 0 -> x is fp32 always; 1 -> branch on *flag (bf16 vs fp32).
__global__ __launch_bounds__(256) void gemm_fused_kernel(const void* __restrict__ xin,
                                                         const float* __restrict__ params,
                                                         const unsigned int* __restrict__ flag,
                                                         int xsel,
                                                         unsigned int* __restrict__ hb2,
                                                         float* __restrict__ el,
                                                         float* __restrict__ er,
                                                         unsigned int* __restrict__ gmax,
                                                         int M) {
    __shared__ float xT[16][64];
    __shared__ float wS[16][128];
    __shared__ unsigned int smax[4];
    const float* W = params;
    unsigned int isb = xsel ? *flag : 0u;
    int t = threadIdx.x;
    if (t < 4) smax[t] = 0u;  // ord 0 is the minimum encoding
    int row0 = blockIdx.x * 64;
    int c0 = (t & 15) * 8;
    int r0 = (t >> 4) * 4;
    int xr = t >> 2;
    int xk = (t & 3) * 4;
    int wr = t >> 4;
    int wc = (t & 15) * 8;

    float acc[4][8];
#pragma unroll
    for (int i = 0; i < 4; i++)
#pragma unroll
        for (int j = 0; j < 8; j++) acc[i][j] = 0.f;

    for (int kc = 0; kc < 8; ++kc) {
        float4 xa = make_float4(0.f, 0.f, 0.f, 0.f);
        int grow = row0 + xr;
        if (grow < M) {
            int base = grow * 128 + kc * 16 + xk;
            if (isb) {
                ushort4 u = *(const ushort4*)((const unsigned short*)xin + base);
                xa = make_float4(u2f(u.x), u2f(u.y), u2f(u.z), u2f(u.w));
            } else {
                xa = *(const float4*)((const float*)xin + base);
            }
        }
        xT[xk + 0][xr] = xa.x; xT[xk + 1][xr] = xa.y;
        xT[xk + 2][xr] = xa.z; xT[xk + 3][xr] = xa.w;
        float4 wa = *(const float4*)(W + (kc * 16 + wr) * 128 + wc);
        float4 wb = *(const float4*)(W + (kc * 16 + wr) * 128 + wc + 4);
        *(float4*)&wS[wr][wc] = wa;
        *(float4*)&wS[wr][wc + 4] = wb;
        __syncthreads();
#pragma unroll
        for (int k = 0; k < 16; ++k) {
            float4 a = *(const float4*)&xT[k][r0];
            float4 b0 = *(const float4*)&wS[k][c0];
            float4 b1 = *(const float4*)&wS[k][c0 + 4];
            float av[4] = {a.x, a.y, a.z, a.w};
            float bv[8] = {b0.x, b0.y, b0.z, b0.w, b1.x, b1.y, b1.z, b1.w};
#pragma unroll
            for (int i = 0; i < 4; i++)
#pragma unroll
                for (int j = 0; j < 8; j++) acc[i][j] = fmaf(av[i], bv[j], acc[i][j]);
        }
        __syncthreads();
    }

    // --- epilogue: bf16 h store + el/er dots + per-head global el max ---
    int lane = t & 63;
    float al8[8], ar8[8];
#pragma unroll
    for (int j = 0; j < 8; j++) {
        al8[j] = params[16384 + c0 + j];
        ar8[j] = params[16512 + c0 + j];
    }
    int head = (lane & 15) >> 2;
    float elmax = -INFINITY;

#pragma unroll
    for (int i = 0; i < 4; i++) {
        int row = row0 + r0 + i;
        bool ok = row < M;
        if (ok) {
            unsigned int u[4];
#pragma unroll
            for (int j = 0; j < 4; j++) {
                __hip_bfloat16 p0 = __float2bfloat16(acc[i][2 * j]);
                __hip_bfloat16 p1 = __float2bfloat16(acc[i][2 * j + 1]);
                u[j] = (unsigned int)(*(unsigned short*)&p0)
                     | ((unsigned int)(*(unsigned short*)&p1) << 16);
            }
            *(uint4*)(hb2 + row * 64 + (c0 >> 1)) = make_uint4(u[0], u[1], u[2], u[3]);
        }
        float e_l = 0.f, e_r = 0.f;
#pragma unroll
        for (int j = 0; j < 8; j++) {
            e_l = fmaf(acc[i][j], al8[j], e_l);
            e_r = fmaf(acc[i][j], ar8[j], e_r);
        }
        e_l += __shfl_xor(e_l, 1); e_l += __shfl_xor(e_l, 2);
        e_r += __shfl_xor(e_r, 1); e_r += __shfl_xor(e_r, 2);
        if (ok && (lane & 3) == 0) {
            el[row * 4 + head] = e_l;
            er[row * 4 + head] = e_r;
            elmax = fmaxf(elmax, e_l);
        }
    }
    // reduce elmax across lanes sharing (lane&15)==head*4: strides 16,32
    elmax = fmaxf(elmax, __shfl_xor(elmax, 16));
    elmax = fmaxf(elmax, __shfl_xor(elmax, 32));
    __syncthreads();  // smax init visible
    if ((lane & 15) == 0 || (lane & 15) == 4 || (lane & 15) == 8 || (lane & 15) == 12) {
        if (elmax > -INFINITY) atomicMax(&smax[head], f2ord(elmax));
    }
    __syncthreads();
    if (t < 4) atomicMax(&gmax[t], smax[t]);
}

// ---------- fused: single-pass (bounded-max) softmax agg + bias + LN + ELU ----------
// One wave per dst node. Scoring lane = slot*4 + sh (16 edges x 4 heads / batch).
// Channels: lane owns (2*lane, 2*lane+1), channel head hd = lane>>4.
template <bool LAST>
__global__ __launch_bounds__(256) void agg_ln_kernel(const int* __restrict__ offs,
                                                     const int* __restrict__ esrc,
                                                     const float* __restrict__ el,
                                                     const float* __restrict__ er,
                                                     const unsigned int* __restrict__ hb2,
                                                     const float* __restrict__ params,
                                                     const unsigned int* __restrict__ gmax,
                                                     const unsigned int* __restrict__ flag,
                                                     float* __restrict__ x_next,
                                                     void* __restrict__ out) {
    int node = (blockIdx.x * 256 + threadIdx.x) >> 6;
    int lane = threadIdx.x & 63;
    if (node >= N_NODES) return;
    int e0 = offs[node], e1 = offs[node + 1];
    int d = e1 - e0;
    int sh = lane & 3;
    int slot = lane >> 2;
    float er_s = er[node * 4 + sh];
    // upper bound of max over edges: leaky monotone => leaky(gmax_el + er) >= leaky(el_s + er)
    float M = leaky(ord2f(gmax[sh]) + er_s);

    int hd = lane >> 4;
    int c0 = lane * 2;

    float lsum = 0.f, a0 = 0.f, a1 = 0.f;
    for (int b0 = 0; b0 < d; b0 += 16) {
        int idx = b0 + slot;
        float ex = 0.f;
        int s = 0;
        if (idx < d) {
            s = esrc[e0 + idx];
            ex = __expf(leaky(el[s * 4 + sh] + er_s) - M);
        }
        lsum += ex;
        // pack (s, f16(ex)) -> one bpermute per edge
        _Float16 e16 = (_Float16)ex;
        unsigned int pk = ((unsigned int)s << 16)
                        | (unsigned int)__builtin_bit_cast(unsigned short, e16);
        int nb = min(16, d - b0);
        if (nb == 16) {
#pragma unroll
            for (int j = 0; j < 16; ++j) {
                unsigned int q = __shfl(pk, j * 4 + hd);
                int sj = q >> 16;
                float exj = (float)__builtin_bit_cast(_Float16, (unsigned short)(q & 0xFFFFu));
                unsigned int p = hb2[sj * 64 + lane];
                a0 = fmaf(exj, u2f((unsigned short)(p & 0xFFFFu)), a0);
                a1 = fmaf(exj, __uint_as_float(p & 0xFFFF0000u), a1);
            }
        } else {
            for (int j = 0; j < nb; ++j) {
                unsigned int q = __shfl(pk, j * 4 + hd);
                int sj = q >> 16;
                float exj = (float)__builtin_bit_cast(_Float16, (unsigned short)(q & 0xFFFFu));
                unsigned int p = hb2[sj * 64 + lane];
                a0 = fmaf(exj, u2f((unsigned short)(p & 0xFFFFu)), a0);
                a1 = fmaf(exj, __uint_as_float(p & 0xFFFF0000u), a1);
            }
        }
    }
#pragma unroll
    for (int off = 4; off <= 32; off <<= 1) lsum += __shfl_xor(lsum, off);
    float l = __shfl(lsum, hd);

    float inv = 1.f / fmaxf(l, 1e-9f);
    const float* b  = params + 16640;
    const float* g  = params + 16768;
    const float* be = params + 16896;
    float v0 = fmaf(a0, inv, b[c0]);
    float v1 = fmaf(a1, inv, b[c0 + 1]);

    float s = v0 + v1;
#pragma unroll
    for (int off = 32; off >= 1; off >>= 1) s += __shfl_xor(s, off);
    float mu = s * (1.f / 128.f);
    float q0 = v0 - mu, q1 = v1 - mu;
    float vs = q0 * q0 + q1 * q1;
#pragma unroll
    for (int off = 32; off >= 1; off >>= 1) vs += __shfl_xor(vs, off);
    float rstd = rsqrtf(vs * (1.f / 128.f) + LN_EPS);
    float y0 = q0 * rstd * g[c0] + be[c0];
    float y1 = q1 * rstd * g[c0 + 1] + be[c0 + 1];
    y0 = y0 > 0.f ? y0 : expm1f(y0);
    y1 = y1 > 0.f ? y1 : expm1f(y1);

    if (LAST) {
        if (*flag) {
            __hip_bfloat16 o0 = __float2bfloat16(y0);
            __hip_bfloat16 o1 = __float2bfloat16(y1);
            unsigned int packed = (unsigned int)(*(unsigned short*)&o0)
                                | ((unsigned int)(*(unsigned short*)&o1) << 16);
            ((unsigned int*)out)[node * 64 + lane] = packed;
        } else {
            ((float2*)out)[node * 64 + lane] = make_float2(y0, y1);
        }
    } else {
        ((float2*)x_next)[node * 64 + lane] = make_float2(y0, y1);
    }
}

extern "C" void kernel_launch(void* const* d_in, const int* in_sizes, int n_in,
                              void* d_out, int out_size, void* d_ws, size_t ws_size,
                              hipStream_t stream) {
    const void* features = d_in[0];
    const int* src = (const int*)d_in[1];
    const int* dst = (const int*)d_in[2];

    char* w = (char*)d_ws;
    float* xbuf = (float*)w;                               // 25.6 MB (layer-2 input, fp32)
    unsigned int* hb = (unsigned int*)(w + 25600000);      // 12.8 MB (h bf16 packed)
    float* el = (float*)(w + 38400000);                    // 800 KB
    float* er = (float*)(w + 39200000);                    // 800 KB
    float* params0 = (float*)(w + 40000000);               // 68 KB
    float* params1 = params0 + PARAM_FLOATS;               // 68 KB
    int* offs = (int*)(w + 40137000);                      // 50001 ints
    int* deg  = (int*)(w + 40338000);                      // 50000 ints
    int* esrc = (int*)(w + 40539000);                      // 800000 ints
    int* bsum = (int*)(w + 43739008);                      // 196 ints
    unsigned int* flag  = (unsigned int*)(w + 43740032);
    unsigned int* gmax0 = (unsigned int*)(w + 43740096);   // 4 uints
    unsigned int* gmax1 = (unsigned int*)(w + 43740160);   // 4 uints

    detect_kernel<<<1, 256, 0, stream>>>((const unsigned int*)d_in[3], flag, gmax0, gmax1);
    cvt_params_kernel<<<(PARAM_FLOATS + 255) / 256, 256, 0, stream>>>(
        d_in[3], d_in[4], d_in[5], d_in[6], d_in[7], d_in[8], flag, params0);
    cvt_params_kernel<<<(PARAM_FLOATS + 255) / 256, 256, 0, stream>>>(
        d_in[9], d_in[10], d_in[11], d_in[12], d_in[13], d_in[14], flag, params1);

    hipMemsetAsync(deg, 0, N_NODES * sizeof(int), stream);
    hist_kernel<<<(E_EDGES + 255) / 256, 256, 0, stream>>>(dst, deg);
    scan_reduce_kernel<<<SCAN_BLOCKS, 256, 0, stream>>>(deg, bsum);
    scan_bsum_kernel<<<1, 256, 0, stream>>>(bsum);
    scan_write_kernel<<<SCAN_BLOCKS, 256, 0, stream>>>(deg, bsum, offs);
    hipMemsetAsync(deg, 0, N_NODES * sizeof(int), stream);
    scatter_kernel<<<(E_EDGES + 255) / 256, 256, 0, stream>>>(src, dst, offs, deg, esrc);

    for (int l = 0; l < 2; ++l) {
        float* params = (l == 0) ? params0 : params1;
        unsigned int* gmax = (l == 0) ? gmax0 : gmax1;
        const void* x = (l == 0) ? features : (const void*)xbuf;
        int xsel = (l == 0) ? 1 : 0;

        gemm_fused_kernel<<<(N_NODES + 63) / 64, 256, 0, stream>>>(
            x, params, flag, xsel, hb, el, er, gmax, N_NODES);
        if (l == 0) {
            agg_ln_kernel<false><<<(N_NODES * 64 + 255) / 256, 256, 0, stream>>>(
                offs, esrc, el, er, hb, params, gmax, flag, xbuf, nullptr);
        } else {
            agg_ln_kernel<true><<<(N_NODES * 64 + 255) / 256, 256, 0, stream>>>(
                offs, esrc, el, er, hb, params, gmax, flag, nullptr, d_out);
        }
    }
}

// Round 10
// 307.192 us; speedup vs baseline: 1.8013x; 1.1746x over previous
//
#include <hip/hip_runtime.h>
#include <hip/hip_bf16.h>

#define N_NODES 50000
#define E_EDGES 800000
#define HID 128
#define HEADS 4
#define NEG_SLOPE 0.2f
#define LN_EPS 1e-5f
#define PARAM_FLOATS 17024  // W(16384) al(128) ar(128) b(128) g(128) be(128)
#define NBUCK 196           // buckets of 256 nodes
#define BCAP 6144           // max edges/bucket (mean 4096, sigma 64 -> 32 sigma margin)
#define BIN_CH 2048         // edges per bin block

__device__ __forceinline__ float bf2f(__hip_bfloat16 b) { return __bfloat162float(b); }
__device__ __forceinline__ float u2f(unsigned short u) {
    return __uint_as_float(((unsigned int)u) << 16);
}
__device__ __forceinline__ float leaky(float v) { return v > 0.f ? v : v * NEG_SLOPE; }

// order-preserving float<->uint for atomicMax over signed floats
__device__ __forceinline__ unsigned int f2ord(float f) {
    unsigned int u = __float_as_uint(f);
    return (u & 0x80000000u) ? ~u : (u | 0x80000000u);
}
__device__ __forceinline__ float ord2f(unsigned int u) {
    u = (u & 0x80000000u) ? (u & 0x7FFFFFFFu) : ~u;
    return __uint_as_float(u);
}

// ---------- runtime dtype detection + gmax init ----------
__global__ __launch_bounds__(256) void detect_kernel(const unsigned int* __restrict__ w0,
                                                     unsigned int* __restrict__ flag,
                                                     unsigned int* __restrict__ gmax0,
                                                     unsigned int* __restrict__ gmax1) {
    int t = threadIdx.x;
    if (t < 4) {
        gmax0[t] = f2ord(-INFINITY);
        gmax1[t] = f2ord(-INFINITY);
    }
    int cnt = 0;
    for (int i = t; i < 4096; i += 256) {
        unsigned int lo = (w0[i] & 0xFFFFu) << 16;
        float v = fabsf(__uint_as_float(lo));
        if (v >= 1e-6f && v <= 1.0f) cnt++;
    }
    __shared__ int sh[4];
#pragma unroll
    for (int off = 32; off >= 1; off >>= 1) cnt += __shfl_xor(cnt, off);
    if ((t & 63) == 0) sh[t >> 6] = cnt;
    __syncthreads();
    if (t == 0) *flag = ((sh[0] + sh[1] + sh[2] + sh[3]) > 2048) ? 1u : 0u;
}

__device__ __forceinline__ float load_any(const void* p, int i, unsigned int isbf16) {
    return isbf16 ? bf2f(((const __hip_bfloat16*)p)[i]) : ((const float*)p)[i];
}

__global__ __launch_bounds__(256) void cvt_params_kernel(const void* W, const void* al,
                                                         const void* ar, const void* b,
                                                         const void* g, const void* be,
                                                         const unsigned int* __restrict__ flag,
                                                         float* __restrict__ out) {
    int i = blockIdx.x * 256 + threadIdx.x;
    if (i >= PARAM_FLOATS) return;
    unsigned int isb = *flag;
    const void* src; int off;
    if (i < 16384)      { src = W;  off = i; }
    else if (i < 16512) { src = al; off = i - 16384; }
    else if (i < 16640) { src = ar; off = i - 16512; }
    else if (i < 16768) { src = b;  off = i - 16640; }
    else if (i < 16896) { src = g;  off = i - 16768; }
    else                { src = be; off = i - 16896; }
    out[i] = load_any(src, off, isb);
}

// ---------- CSR build, phase 1: bin edges by dst>>8 with block-aggregated cursors ----------
__global__ __launch_bounds__(256) void bin_kernel(const int* __restrict__ src,
                                                  const int* __restrict__ dst,
                                                  int* __restrict__ bcnt,
                                                  int2* __restrict__ ebuf) {
    __shared__ int lh[NBUCK];
    __shared__ int lbase[NBUCK];
    int t = threadIdx.x;
    for (int i = t; i < NBUCK; i += 256) lh[i] = 0;
    __syncthreads();
    int e0 = blockIdx.x * BIN_CH;
    int n = min(BIN_CH, E_EDGES - e0);
    int s8[8], d8[8], rk[8];
#pragma unroll
    for (int j = 0; j < 8; ++j) {
        int k = j * 256 + t;
        if (k < n) {
            s8[j] = src[e0 + k];
            d8[j] = dst[e0 + k];
            rk[j] = atomicAdd(&lh[d8[j] >> 8], 1);
        }
    }
    __syncthreads();
    for (int i = t; i < NBUCK; i += 256) lbase[i] = atomicAdd(&bcnt[i], lh[i]);
    __syncthreads();
#pragma unroll
    for (int j = 0; j < 8; ++j) {
        int k = j * 256 + t;
        if (k < n) {
            int b = d8[j] >> 8;
            int pos = lbase[b] + rk[j];
            if (pos < BCAP) ebuf[b * BCAP + pos] = make_int2(s8[j], d8[j]);
        }
    }
}

// ---------- phase 1b: exclusive scan of bucket counts -> bucket bases ----------
__global__ __launch_bounds__(256) void bscan_kernel(const int* __restrict__ bcnt,
                                                    int* __restrict__ bbase) {
    int t = threadIdx.x;
    int lane = t & 63, wid = t >> 6;
    int v = (t < NBUCK) ? min(bcnt[t], BCAP) : 0;
    int x = v;
#pragma unroll
    for (int o = 1; o < 64; o <<= 1) {
        int y = __shfl_up(x, o);
        if (lane >= o) x += y;
    }
    __shared__ int wt[4];
    if (lane == 63) wt[wid] = x;
    __syncthreads();
    int add = 0;
    for (int j = 0; j < wid; j++) add += wt[j];
    if (t < NBUCK) bbase[t] = add + x - v;  // exclusive
}

// ---------- phase 2: per-bucket LDS counting sort; writes offs + coalesced esrc ----------
__global__ __launch_bounds__(256) void csr_kernel(const int* __restrict__ bcnt,
                                                  const int* __restrict__ bbase,
                                                  const int2* __restrict__ ebuf,
                                                  int* __restrict__ offs,
                                                  int* __restrict__ esrc) {
    __shared__ int cnt[256];
    __shared__ int wt[4];
    __shared__ int out_lds[BCAP];
    int b = blockIdx.x, t = threadIdx.x;
    int n = min(bcnt[b], BCAP);
    int base = bbase[b];
    const int2* eb = ebuf + b * BCAP;
    cnt[t] = 0;
    __syncthreads();
    for (int i = t; i < n; i += 256) atomicAdd(&cnt[eb[i].y & 255], 1);
    __syncthreads();
    // exclusive scan of cnt[256]
    int lane = t & 63, wid = t >> 6;
    int v = cnt[t];
    int x = v;
#pragma unroll
    for (int o = 1; o < 64; o <<= 1) {
        int y = __shfl_up(x, o);
        if (lane >= o) x += y;
    }
    if (lane == 63) wt[wid] = x;
    __syncthreads();
    int add = 0;
    for (int j = 0; j < wid; j++) add += wt[j];
    int excl = add + x - v;
    int node = b * 256 + t;
    if (node <= N_NODES) offs[node] = base + excl;
    __syncthreads();
    cnt[t] = excl;  // cursor
    __syncthreads();
    for (int i = t; i < n; i += 256) {
        int2 e = eb[i];
        int p = atomicAdd(&cnt[e.y & 255], 1);
        out_lds[p] = e.x;
    }
    __syncthreads();
    for (int i = t; i < n; i += 256) esrc[base + i] = out_lds[i];
}

// ---------- fused GEMM: h = x @ W -> bf16 h, el/er, per-head global el-max ----------
__global__ __launch_bounds__(256) void gemm_fused_kernel(const void* __restrict__ xin,
                                                         const float* __restrict__ params,
                                                         const unsigned int* __restrict__ flag,
                                                         int xsel,
                                                         unsigned int* __restrict__ hb2,
                                                         float* __restrict__ el,
                                                         float* __restrict__ er,
                                                         unsigned int* __restrict__ gmax,
                                                         int M) {
    __shared__ float xT[16][64];
    __shared__ float wS[16][128];
    __shared__ unsigned int smax[4];
    const float* W = params;
    unsigned int isb = xsel ? *flag : 0u;
    int t = threadIdx.x;
    if (t < 4) smax[t] = 0u;
    int row0 = blockIdx.x * 64;
    int c0 = (t & 15) * 8;
    int r0 = (t >> 4) * 4;
    int xr = t >> 2;
    int xk = (t & 3) * 4;
    int wr = t >> 4;
    int wc = (t & 15) * 8;

    float acc[4][8];
#pragma unroll
    for (int i = 0; i < 4; i++)
#pragma unroll
        for (int j = 0; j < 8; j++) acc[i][j] = 0.f;

    for (int kc = 0; kc < 8; ++kc) {
        float4 xa = make_float4(0.f, 0.f, 0.f, 0.f);
        int grow = row0 + xr;
        if (grow < M) {
            int base = grow * 128 + kc * 16 + xk;
            if (isb) {
                ushort4 u = *(const ushort4*)((const unsigned short*)xin + base);
                xa = make_float4(u2f(u.x), u2f(u.y), u2f(u.z), u2f(u.w));
            } else {
                xa = *(const float4*)((const float*)xin + base);
            }
        }
        xT[xk + 0][xr] = xa.x; xT[xk + 1][xr] = xa.y;
        xT[xk + 2][xr] = xa.z; xT[xk + 3][xr] = xa.w;
        float4 wa = *(const float4*)(W + (kc * 16 + wr) * 128 + wc);
        float4 wb = *(const float4*)(W + (kc * 16 + wr) * 128 + wc + 4);
        *(float4*)&wS[wr][wc] = wa;
        *(float4*)&wS[wr][wc + 4] = wb;
        __syncthreads();
#pragma unroll
        for (int k = 0; k < 16; ++k) {
            float4 a = *(const float4*)&xT[k][r0];
            float4 b0 = *(const float4*)&wS[k][c0];
            float4 b1 = *(const float4*)&wS[k][c0 + 4];
            float av[4] = {a.x, a.y, a.z, a.w};
            float bv[8] = {b0.x, b0.y, b0.z, b0.w, b1.x, b1.y, b1.z, b1.w};
#pragma unroll
            for (int i = 0; i < 4; i++)
#pragma unroll
                for (int j = 0; j < 8; j++) acc[i][j] = fmaf(av[i], bv[j], acc[i][j]);
        }
        __syncthreads();
    }

    int lane = t & 63;
    float al8[8], ar8[8];
#pragma unroll
    for (int j = 0; j < 8; j++) {
        al8[j] = params[16384 + c0 + j];
        ar8[j] = params[16512 + c0 + j];
    }
    int head = (lane & 15) >> 2;
    float elmax = -INFINITY;

#pragma unroll
    for (int i = 0; i < 4; i++) {
        int row = row0 + r0 + i;
        bool ok = row < M;
        if (ok) {
            unsigned int u[4];
#pragma unroll
            for (int j = 0; j < 4; j++) {
                __hip_bfloat16 p0 = __float2bfloat16(acc[i][2 * j]);
                __hip_bfloat16 p1 = __float2bfloat16(acc[i][2 * j + 1]);
                u[j] = (unsigned int)(*(unsigned short*)&p0)
                     | ((unsigned int)(*(unsigned short*)&p1) << 16);
            }
            *(uint4*)(hb2 + row * 64 + (c0 >> 1)) = make_uint4(u[0], u[1], u[2], u[3]);
        }
        float e_l = 0.f, e_r = 0.f;
#pragma unroll
        for (int j = 0; j < 8; j++) {
            e_l = fmaf(acc[i][j], al8[j], e_l);
            e_r = fmaf(acc[i][j], ar8[j], e_r);
        }
        e_l += __shfl_xor(e_l, 1); e_l += __shfl_xor(e_l, 2);
        e_r += __shfl_xor(e_r, 1); e_r += __shfl_xor(e_r, 2);
        if (ok && (lane & 3) == 0) {
            el[row * 4 + head] = e_l;
            er[row * 4 + head] = e_r;
            elmax = fmaxf(elmax, e_l);
        }
    }
    elmax = fmaxf(elmax, __shfl_xor(elmax, 16));
    elmax = fmaxf(elmax, __shfl_xor(elmax, 32));
    __syncthreads();
    if ((lane & 15) == 0 || (lane & 15) == 4 || (lane & 15) == 8 || (lane & 15) == 12) {
        if (elmax > -INFINITY) atomicMax(&smax[head], f2ord(elmax));
    }
    __syncthreads();
    if (t < 4) atomicMax(&gmax[t], smax[t]);
}

// ---------- fused: single-pass (bounded-max) softmax agg + bias + LN + ELU ----------
template <bool LAST>
__global__ __launch_bounds__(256) void agg_ln_kernel(const int* __restrict__ offs,
                                                     const int* __restrict__ esrc,
                                                     const float* __restrict__ el,
                                                     const float* __restrict__ er,
                                                     const unsigned int* __restrict__ hb2,
                                                     const float* __restrict__ params,
                                                     const unsigned int* __restrict__ gmax,
                                                     const unsigned int* __restrict__ flag,
                                                     float* __restrict__ x_next,
                                                     void* __restrict__ out) {
    int node = (blockIdx.x * 256 + threadIdx.x) >> 6;
    int lane = threadIdx.x & 63;
    if (node >= N_NODES) return;
    int e0 = offs[node], e1 = offs[node + 1];
    int d = e1 - e0;
    int sh = lane & 3;
    int slot = lane >> 2;
    float er_s = er[node * 4 + sh];
    float M = leaky(ord2f(gmax[sh]) + er_s);

    int hd = lane >> 4;
    int c0 = lane * 2;

    float lsum = 0.f, a0 = 0.f, a1 = 0.f;
    for (int b0 = 0; b0 < d; b0 += 16) {
        int idx = b0 + slot;
        float ex = 0.f;
        int s = 0;
        if (idx < d) {
            s = esrc[e0 + idx];
            ex = __expf(leaky(el[s * 4 + sh] + er_s) - M);
        }
        lsum += ex;
        _Float16 e16 = (_Float16)ex;
        unsigned int pk = ((unsigned int)s << 16)
                        | (unsigned int)__builtin_bit_cast(unsigned short, e16);
        int nb = min(16, d - b0);
        if (nb == 16) {
#pragma unroll
            for (int j = 0; j < 16; ++j) {
                unsigned int q = __shfl(pk, j * 4 + hd);
                int sj = q >> 16;
                float exj = (float)__builtin_bit_cast(_Float16, (unsigned short)(q & 0xFFFFu));
                unsigned int p = hb2[sj * 64 + lane];
                a0 = fmaf(exj, u2f((unsigned short)(p & 0xFFFFu)), a0);
                a1 = fmaf(exj, __uint_as_float(p & 0xFFFF0000u), a1);
            }
        } else {
            for (int j = 0; j < nb; ++j) {
                unsigned int q = __shfl(pk, j * 4 + hd);
                int sj = q >> 16;
                float exj = (float)__builtin_bit_cast(_Float16, (unsigned short)(q & 0xFFFFu));
                unsigned int p = hb2[sj * 64 + lane];
                a0 = fmaf(exj, u2f((unsigned short)(p & 0xFFFFu)), a0);
                a1 = fmaf(exj, __uint_as_float(p & 0xFFFF0000u), a1);
            }
        }
    }
#pragma unroll
    for (int off = 4; off <= 32; off <<= 1) lsum += __shfl_xor(lsum, off);
    float l = __shfl(lsum, hd);

    float inv = 1.f / fmaxf(l, 1e-9f);
    const float* b  = params + 16640;
    const float* g  = params + 16768;
    const float* be = params + 16896;
    float v0 = fmaf(a0, inv, b[c0]);
    float v1 = fmaf(a1, inv, b[c0 + 1]);

    float s = v0 + v1;
#pragma unroll
    for (int off = 32; off >= 1; off >>= 1) s += __shfl_xor(s, off);
    float mu = s * (1.f / 128.f);
    float q0 = v0 - mu, q1 = v1 - mu;
    float vs = q0 * q0 + q1 * q1;
#pragma unroll
    for (int off = 32; off >= 1; off >>= 1) vs += __shfl_xor(vs, off);
    float rstd = rsqrtf(vs * (1.f / 128.f) + LN_EPS);
    float y0 = q0 * rstd * g[c0] + be[c0];
    float y1 = q1 * rstd * g[c0 + 1] + be[c0 + 1];
    y0 = y0 > 0.f ? y0 : expm1f(y0);
    y1 = y1 > 0.f ? y1 : expm1f(y1);

    if (LAST) {
        if (*flag) {
            __hip_bfloat16 o0 = __float2bfloat16(y0);
            __hip_bfloat16 o1 = __float2bfloat16(y1);
            unsigned int packed = (unsigned int)(*(unsigned short*)&o0)
                                | ((unsigned int)(*(unsigned short*)&o1) << 16);
            ((unsigned int*)out)[node * 64 + lane] = packed;
        } else {
            ((float2*)out)[node * 64 + lane] = make_float2(y0, y1);
        }
    } else {
        ((float2*)x_next)[node * 64 + lane] = make_float2(y0, y1);
    }
}

extern "C" void kernel_launch(void* const* d_in, const int* in_sizes, int n_in,
                              void* d_out, int out_size, void* d_ws, size_t ws_size,
                              hipStream_t stream) {
    const void* features = d_in[0];
    const int* src = (const int*)d_in[1];
    const int* dst = (const int*)d_in[2];

    char* w = (char*)d_ws;
    float* xbuf = (float*)w;                               // 25.6 MB (layer-2 input, fp32)
    unsigned int* hb = (unsigned int*)(w + 25600000);      // 12.8 MB (h bf16 packed)
    float* el = (float*)(w + 38400000);                    // 800 KB
    float* er = (float*)(w + 39200000);                    // 800 KB
    float* params0 = (float*)(w + 40000000);               // 68 KB
    float* params1 = params0 + PARAM_FLOATS;               // 68 KB
    int* offs = (int*)(w + 40137000);                      // 50001 ints
    int* esrc = (int*)(w + 40539000);                      // 800000 ints -> ends 43,739,000
    int* bcnt  = (int*)(w + 43739008);                     // 196 ints
    int* bbase = (int*)(w + 43740032);                     // 196 ints
    unsigned int* flag  = (unsigned int*)(w + 43740864);
    unsigned int* gmax0 = (unsigned int*)(w + 43740928);   // 4 uints
    unsigned int* gmax1 = (unsigned int*)(w + 43740992);   // 4 uints
    int2* ebuf = (int2*)(w + 43741184);                    // 196*6144*8 = 9.63 MB -> 53.37 MB

    detect_kernel<<<1, 256, 0, stream>>>((const unsigned int*)d_in[3], flag, gmax0, gmax1);
    cvt_params_kernel<<<(PARAM_FLOATS + 255) / 256, 256, 0, stream>>>(
        d_in[3], d_in[4], d_in[5], d_in[6], d_in[7], d_in[8], flag, params0);
    cvt_params_kernel<<<(PARAM_FLOATS + 255) / 256, 256, 0, stream>>>(
        d_in[9], d_in[10], d_in[11], d_in[12], d_in[13], d_in[14], flag, params1);

    hipMemsetAsync(bcnt, 0, NBUCK * sizeof(int), stream);
    bin_kernel<<<(E_EDGES + BIN_CH - 1) / BIN_CH, 256, 0, stream>>>(src, dst, bcnt, ebuf);
    bscan_kernel<<<1, 256, 0, stream>>>(bcnt, bbase);
    csr_kernel<<<NBUCK, 256, 0, stream>>>(bcnt, bbase, ebuf, offs, esrc);

    for (int l = 0; l < 2; ++l) {
        float* params = (l == 0) ? params0 : params1;
        unsigned int* gmax = (l == 0) ? gmax0 : gmax1;
        const void* x = (l == 0) ? features : (const void*)xbuf;
        int xsel = (l == 0) ? 1 : 0;

        gemm_fused_kernel<<<(N_NODES + 63) / 64, 256, 0, stream>>>(
            x, params, flag, xsel, hb, el, er, gmax, N_NODES);
        if (l == 0) {
            agg_ln_kernel<false><<<(N_NODES * 64 + 255) / 256, 256, 0, stream>>>(
                offs, esrc, el, er, hb, params, gmax, flag, xbuf, nullptr);
        } else {
            agg_ln_kernel<true><<<(N_NODES * 64 + 255) / 256, 256, 0, stream>>>(
                offs, esrc, el, er, hb, params, gmax, flag, nullptr, d_out);
        }
    }
}

// Round 11
// 291.089 us; speedup vs baseline: 1.9010x; 1.0553x over previous
//
#include <hip/hip_runtime.h>
#include <hip/hip_bf16.h>

#define N_NODES 50000
#define E_EDGES 800000
#define HID 128
#define HEADS 4
#define NEG_SLOPE 0.2f
#define LN_EPS 1e-5f
#define PARAM_FLOATS 17024  // [unused W fp32 region](16384) al(128) ar(128) b(128) g(128) be(128)
#define NBUCK 196           // buckets of 256 nodes
#define BCAP 6144           // max edges/bucket
#define BIN_CH 2048         // edges per bin block

typedef __attribute__((ext_vector_type(8))) short short8;
typedef __attribute__((ext_vector_type(4))) float float4v;

__device__ __forceinline__ float bf2f(__hip_bfloat16 b) { return __bfloat162float(b); }
__device__ __forceinline__ float u2f(unsigned short u) {
    return __uint_as_float(((unsigned int)u) << 16);
}
__device__ __forceinline__ short bfb(float f) {
    __hip_bfloat16 h = __float2bfloat16(f);
    return *(short*)&h;
}
__device__ __forceinline__ float leaky(float v) { return v > 0.f ? v : v * NEG_SLOPE; }

__device__ __forceinline__ unsigned int f2ord(float f) {
    unsigned int u = __float_as_uint(f);
    return (u & 0x80000000u) ? ~u : (u | 0x80000000u);
}
__device__ __forceinline__ float ord2f(unsigned int u) {
    u = (u & 0x80000000u) ? (u & 0x7FFFFFFFu) : ~u;
    return __uint_as_float(u);
}

// ---------- runtime dtype detection + gmax init ----------
__global__ __launch_bounds__(256) void detect_kernel(const unsigned int* __restrict__ w0,
                                                     unsigned int* __restrict__ flag,
                                                     unsigned int* __restrict__ gmax0,
                                                     unsigned int* __restrict__ gmax1) {
    int t = threadIdx.x;
    if (t < 4) {
        gmax0[t] = f2ord(-INFINITY);
        gmax1[t] = f2ord(-INFINITY);
    }
    int cnt = 0;
    for (int i = t; i < 4096; i += 256) {
        unsigned int lo = (w0[i] & 0xFFFFu) << 16;
        float v = fabsf(__uint_as_float(lo));
        if (v >= 1e-6f && v <= 1.0f) cnt++;
    }
    __shared__ int sh[4];
#pragma unroll
    for (int off = 32; off >= 1; off >>= 1) cnt += __shfl_xor(cnt, off);
    if ((t & 63) == 0) sh[t >> 6] = cnt;
    __syncthreads();
    if (t == 0) *flag = ((sh[0] + sh[1] + sh[2] + sh[3]) > 2048) ? 1u : 0u;
}

__device__ __forceinline__ float load_any(const void* p, int i, unsigned int isbf16) {
    return isbf16 ? bf2f(((const __hip_bfloat16*)p)[i]) : ((const float*)p)[i];
}

// params fp32 block (al/ar/b/g/be at 16384..17024) + Wt bf16 [n][k]
__global__ __launch_bounds__(256) void cvt_params_kernel(const void* W, const void* al,
                                                         const void* ar, const void* b,
                                                         const void* g, const void* be,
                                                         const unsigned int* __restrict__ flag,
                                                         float* __restrict__ out,
                                                         unsigned short* __restrict__ wt) {
    int i = blockIdx.x * 256 + threadIdx.x;
    if (i >= PARAM_FLOATS) return;
    unsigned int isb = *flag;
    if (i < 16384) {
        unsigned short bits;
        if (isb) bits = ((const unsigned short*)W)[i];
        else     { short s = bfb(((const float*)W)[i]); bits = (unsigned short)s; }
        wt[((i & 127) << 7) | (i >> 7)] = bits;  // Wt[n][k] = W[k][n]
        return;
    }
    const void* src; int off;
    if (i < 16512)      { src = al; off = i - 16384; }
    else if (i < 16640) { src = ar; off = i - 16512; }
    else if (i < 16768) { src = b;  off = i - 16640; }
    else if (i < 16896) { src = g;  off = i - 16768; }
    else                { src = be; off = i - 16896; }
    out[i] = load_any(src, off, isb);
}

// ---------- CSR build, phase 1: bin edges by dst>>8 ----------
__global__ __launch_bounds__(256) void bin_kernel(const int* __restrict__ src,
                                                  const int* __restrict__ dst,
                                                  int* __restrict__ bcnt,
                                                  int2* __restrict__ ebuf) {
    __shared__ int lh[NBUCK];
    __shared__ int lbase[NBUCK];
    int t = threadIdx.x;
    for (int i = t; i < NBUCK; i += 256) lh[i] = 0;
    __syncthreads();
    int e0 = blockIdx.x * BIN_CH;
    int n = min(BIN_CH, E_EDGES - e0);
    int s8[8], d8[8], rk[8];
#pragma unroll
    for (int j = 0; j < 8; ++j) {
        int k = j * 256 + t;
        if (k < n) {
            s8[j] = src[e0 + k];
            d8[j] = dst[e0 + k];
            rk[j] = atomicAdd(&lh[d8[j] >> 8], 1);
        }
    }
    __syncthreads();
    for (int i = t; i < NBUCK; i += 256) lbase[i] = atomicAdd(&bcnt[i], lh[i]);
    __syncthreads();
#pragma unroll
    for (int j = 0; j < 8; ++j) {
        int k = j * 256 + t;
        if (k < n) {
            int b = d8[j] >> 8;
            int pos = lbase[b] + rk[j];
            if (pos < BCAP) ebuf[b * BCAP + pos] = make_int2(s8[j], d8[j]);
        }
    }
}

__global__ __launch_bounds__(256) void bscan_kernel(const int* __restrict__ bcnt,
                                                    int* __restrict__ bbase) {
    int t = threadIdx.x;
    int lane = t & 63, wid = t >> 6;
    int v = (t < NBUCK) ? min(bcnt[t], BCAP) : 0;
    int x = v;
#pragma unroll
    for (int o = 1; o < 64; o <<= 1) {
        int y = __shfl_up(x, o);
        if (lane >= o) x += y;
    }
    __shared__ int wt[4];
    if (lane == 63) wt[wid] = x;
    __syncthreads();
    int add = 0;
    for (int j = 0; j < wid; j++) add += wt[j];
    if (t < NBUCK) bbase[t] = add + x - v;  // exclusive
}

__global__ __launch_bounds__(256) void csr_kernel(const int* __restrict__ bcnt,
                                                  const int* __restrict__ bbase,
                                                  const int2* __restrict__ ebuf,
                                                  int* __restrict__ offs,
                                                  int* __restrict__ esrc) {
    __shared__ int cnt[256];
    __shared__ int wt[4];
    __shared__ int out_lds[BCAP];
    int b = blockIdx.x, t = threadIdx.x;
    int n = min(bcnt[b], BCAP);
    int base = bbase[b];
    const int2* eb = ebuf + b * BCAP;
    cnt[t] = 0;
    __syncthreads();
    for (int i = t; i < n; i += 256) atomicAdd(&cnt[eb[i].y & 255], 1);
    __syncthreads();
    int lane = t & 63, wid = t >> 6;
    int v = cnt[t];
    int x = v;
#pragma unroll
    for (int o = 1; o < 64; o <<= 1) {
        int y = __shfl_up(x, o);
        if (lane >= o) x += y;
    }
    if (lane == 63) wt[wid] = x;
    __syncthreads();
    int add = 0;
    for (int j = 0; j < wid; j++) add += wt[j];
    int excl = add + x - v;
    int node = b * 256 + t;
    if (node <= N_NODES) offs[node] = base + excl;
    __syncthreads();
    cnt[t] = excl;
    __syncthreads();
    for (int i = t; i < n; i += 256) {
        int2 e = eb[i];
        int p = atomicAdd(&cnt[e.y & 255], 1);
        out_lds[p] = e.x;
    }
    __syncthreads();
    for (int i = t; i < n; i += 256) esrc[base + i] = out_lds[i];
}

// ---------- MFMA GEMM: h = x @ W -> bf16 h, el/er, per-head global el-max ----------
// Block 256 = 4 waves, 64-row tile; wave = 16 rows x 128 cols via 4kt x 8ct mfma 16x16x32.
// mode: 0 = x dtype per *flag (fp32 cvt or bf16); 1 = x is packed bf16 (layer 2).
__global__ __launch_bounds__(256) void gemm_mfma_kernel(const void* __restrict__ xin,
                                                        const unsigned short* __restrict__ wt,
                                                        const float* __restrict__ params,
                                                        const unsigned int* __restrict__ flag,
                                                        int mode,
                                                        unsigned int* __restrict__ hb2,
                                                        float* __restrict__ el,
                                                        float* __restrict__ er,
                                                        unsigned int* __restrict__ gmax,
                                                        int M) {
    __shared__ float ldsC[4][16][132];  // per-wave C tile (padded)
    __shared__ unsigned int smax[4];
    unsigned int isb = mode ? 1u : *flag;
    int t = threadIdx.x;
    if (t < 4) smax[t] = 0u;
    int w = t >> 6, lane = t & 63;
    int m = lane & 15, quad = lane >> 4;
    int row0b = blockIdx.x * 64;
    int arow = row0b + w * 16 + m;
    bool avalid = arow < M;

    float4v acc[8];
#pragma unroll
    for (int i = 0; i < 8; i++) acc[i] = (float4v){0.f, 0.f, 0.f, 0.f};

#pragma unroll
    for (int kt = 0; kt < 4; ++kt) {
        short8 a = (short8){0, 0, 0, 0, 0, 0, 0, 0};
        if (avalid) {
            int base = arow * 128 + kt * 32 + quad * 8;
            if (isb) {
                a = *(const short8*)((const unsigned short*)xin + base);
            } else {
                const float* xp = (const float*)xin + base;
                float4 f0 = *(const float4*)xp;
                float4 f1 = *(const float4*)(xp + 4);
                a = (short8){bfb(f0.x), bfb(f0.y), bfb(f0.z), bfb(f0.w),
                             bfb(f1.x), bfb(f1.y), bfb(f1.z), bfb(f1.w)};
            }
        }
#pragma unroll
        for (int ct = 0; ct < 8; ++ct) {
            short8 b = *(const short8*)(wt + (ct * 16 + m) * 128 + kt * 32 + quad * 8);
            acc[ct] = __builtin_amdgcn_mfma_f32_16x16x32_bf16(a, b, acc[ct], 0, 0, 0);
        }
    }

    // C layout: col = ct*16 + (lane&15), row (in-wave) = quad*4 + r  ->  LDS transpose
#pragma unroll
    for (int ct = 0; ct < 8; ++ct)
#pragma unroll
        for (int r = 0; r < 4; ++r)
            ldsC[w][quad * 4 + r][ct * 16 + m] = acc[ct][r];
    __syncthreads();

    // --- epilogue (same mapping as previous rounds): thread = 4 rows x 8 cols ---
    int c0 = (t & 15) * 8;
    int r0e = (t >> 4) * 4;
    float al8[8], ar8[8];
#pragma unroll
    for (int j = 0; j < 8; j++) {
        al8[j] = params[16384 + c0 + j];
        ar8[j] = params[16512 + c0 + j];
    }
    int head = (lane & 15) >> 2;
    float elmax = -INFINITY;

#pragma unroll
    for (int i = 0; i < 4; i++) {
        int rr = r0e + i;               // 0..63 block-local
        int row = row0b + rr;
        bool ok = row < M;
        const float* ld = &ldsC[rr >> 4][rr & 15][c0];
        float4 h0 = *(const float4*)ld;
        float4 h1 = *(const float4*)(ld + 4);
        float hv[8] = {h0.x, h0.y, h0.z, h0.w, h1.x, h1.y, h1.z, h1.w};
        if (ok) {
            unsigned int u[4];
#pragma unroll
            for (int j = 0; j < 4; j++) {
                u[j] = (unsigned int)(unsigned short)bfb(hv[2 * j])
                     | ((unsigned int)(unsigned short)bfb(hv[2 * j + 1]) << 16);
            }
            *(uint4*)(hb2 + row * 64 + (c0 >> 1)) = make_uint4(u[0], u[1], u[2], u[3]);
        }
        float e_l = 0.f, e_r = 0.f;
#pragma unroll
        for (int j = 0; j < 8; j++) {
            e_l = fmaf(hv[j], al8[j], e_l);
            e_r = fmaf(hv[j], ar8[j], e_r);
        }
        e_l += __shfl_xor(e_l, 1); e_l += __shfl_xor(e_l, 2);
        e_r += __shfl_xor(e_r, 1); e_r += __shfl_xor(e_r, 2);
        if (ok && (lane & 3) == 0) {
            el[row * 4 + head] = e_l;
            er[row * 4 + head] = e_r;
            elmax = fmaxf(elmax, e_l);
        }
    }
    elmax = fmaxf(elmax, __shfl_xor(elmax, 16));
    elmax = fmaxf(elmax, __shfl_xor(elmax, 32));
    __syncthreads();
    if ((lane & 15) == 0 || (lane & 15) == 4 || (lane & 15) == 8 || (lane & 15) == 12) {
        if (elmax > -INFINITY) atomicMax(&smax[head], f2ord(elmax));
    }
    __syncthreads();
    if (t < 4) atomicMax(&gmax[t], smax[t]);
}

// ---------- fused: single-pass (bounded-max) softmax agg + bias + LN + ELU ----------
// x_next written as packed bf16 (uint per channel pair).
template <bool LAST>
__global__ __launch_bounds__(256) void agg_ln_kernel(const int* __restrict__ offs,
                                                     const int* __restrict__ esrc,
                                                     const float* __restrict__ el,
                                                     const float* __restrict__ er,
                                                     const unsigned int* __restrict__ hb2,
                                                     const float* __restrict__ params,
                                                     const unsigned int* __restrict__ gmax,
                                                     const unsigned int* __restrict__ flag,
                                                     unsigned int* __restrict__ x_next,
                                                     void* __restrict__ out) {
    int node = (blockIdx.x * 256 + threadIdx.x) >> 6;
    int lane = threadIdx.x & 63;
    if (node >= N_NODES) return;
    int e0 = offs[node], e1 = offs[node + 1];
    int d = e1 - e0;
    int sh = lane & 3;
    int slot = lane >> 2;
    float er_s = er[node * 4 + sh];
    float M = leaky(ord2f(gmax[sh]) + er_s);

    int hd = lane >> 4;
    int c0 = lane * 2;

    float lsum = 0.f, a0 = 0.f, a1 = 0.f;
    for (int b0 = 0; b0 < d; b0 += 16) {
        int idx = b0 + slot;
        float ex = 0.f;
        int s = 0;
        if (idx < d) {
            s = esrc[e0 + idx];
            ex = __expf(leaky(el[s * 4 + sh] + er_s) - M);
        }
        lsum += ex;
        _Float16 e16 = (_Float16)ex;
        unsigned int pk = ((unsigned int)s << 16)
                        | (unsigned int)__builtin_bit_cast(unsigned short, e16);
        int nb = min(16, d - b0);
        if (nb == 16) {
#pragma unroll
            for (int j = 0; j < 16; ++j) {
                unsigned int q = __shfl(pk, j * 4 + hd);
                int sj = q >> 16;
                float exj = (float)__builtin_bit_cast(_Float16, (unsigned short)(q & 0xFFFFu));
                unsigned int p = hb2[sj * 64 + lane];
                a0 = fmaf(exj, u2f((unsigned short)(p & 0xFFFFu)), a0);
                a1 = fmaf(exj, __uint_as_float(p & 0xFFFF0000u), a1);
            }
        } else {
            for (int j = 0; j < nb; ++j) {
                unsigned int q = __shfl(pk, j * 4 + hd);
                int sj = q >> 16;
                float exj = (float)__builtin_bit_cast(_Float16, (unsigned short)(q & 0xFFFFu));
                unsigned int p = hb2[sj * 64 + lane];
                a0 = fmaf(exj, u2f((unsigned short)(p & 0xFFFFu)), a0);
                a1 = fmaf(exj, __uint_as_float(p & 0xFFFF0000u), a1);
            }
        }
    }
#pragma unroll
    for (int off = 4; off <= 32; off <<= 1) lsum += __shfl_xor(lsum, off);
    float l = __shfl(lsum, hd);

    float inv = 1.f / fmaxf(l, 1e-9f);
    const float* b  = params + 16640;
    const float* g  = params + 16768;
    const float* be = params + 16896;
    float v0 = fmaf(a0, inv, b[c0]);
    float v1 = fmaf(a1, inv, b[c0 + 1]);

    float s = v0 + v1;
#pragma unroll
    for (int off = 32; off >= 1; off >>= 1) s += __shfl_xor(s, off);
    float mu = s * (1.f / 128.f);
    float q0 = v0 - mu, q1 = v1 - mu;
    float vs = q0 * q0 + q1 * q1;
#pragma unroll
    for (int off = 32; off >= 1; off >>= 1) vs += __shfl_xor(vs, off);
    float rstd = rsqrtf(vs * (1.f / 128.f) + LN_EPS);
    float y0 = q0 * rstd * g[c0] + be[c0];
    float y1 = q1 * rstd * g[c0 + 1] + be[c0 + 1];
    y0 = y0 > 0.f ? y0 : expm1f(y0);
    y1 = y1 > 0.f ? y1 : expm1f(y1);

    if (LAST) {
        if (*flag) {
            unsigned int packed = (unsigned int)(unsigned short)bfb(y0)
                                | ((unsigned int)(unsigned short)bfb(y1) << 16);
            ((unsigned int*)out)[node * 64 + lane] = packed;
        } else {
            ((float2*)out)[node * 64 + lane] = make_float2(y0, y1);
        }
    } else {
        unsigned int packed = (unsigned int)(unsigned short)bfb(y0)
                            | ((unsigned int)(unsigned short)bfb(y1) << 16);
        x_next[node * 64 + lane] = packed;
    }
}

extern "C" void kernel_launch(void* const* d_in, const int* in_sizes, int n_in,
                              void* d_out, int out_size, void* d_ws, size_t ws_size,
                              hipStream_t stream) {
    const void* features = d_in[0];
    const int* src = (const int*)d_in[1];
    const int* dst = (const int*)d_in[2];

    char* w = (char*)d_ws;
    unsigned int* xbuf = (unsigned int*)w;                 // 12.8 MB (layer-2 input, packed bf16)
    unsigned int* hb = (unsigned int*)(w + 12800000);      // 12.8 MB (h bf16 packed)
    float* el = (float*)(w + 25600000);                    // 800 KB
    float* er = (float*)(w + 26400000);                    // 800 KB
    float* params0 = (float*)(w + 27200000);               // 68 KB
    float* params1 = params0 + PARAM_FLOATS;               // 68 KB
    unsigned short* wt0 = (unsigned short*)(w + 27337000); // 32 KB
    unsigned short* wt1 = wt0 + 16384;                     // 32 KB
    int* offs = (int*)(w + 27403000);                      // 50001 ints
    int* esrc = (int*)(w + 27604000);                      // 800000 ints -> ends 30,804,000
    int* bcnt  = (int*)(w + 30804992);                     // 196 ints
    int* bbase = (int*)(w + 30806016);                     // 196 ints
    unsigned int* flag  = (unsigned int*)(w + 30806848);
    unsigned int* gmax0 = (unsigned int*)(w + 30806912);   // 4 uints
    unsigned int* gmax1 = (unsigned int*)(w + 30806976);   // 4 uints
    int2* ebuf = (int2*)(w + 30807040);                    // 9.63 MB -> 40.4 MB

    detect_kernel<<<1, 256, 0, stream>>>((const unsigned int*)d_in[3], flag, gmax0, gmax1);
    cvt_params_kernel<<<(PARAM_FLOATS + 255) / 256, 256, 0, stream>>>(
        d_in[3], d_in[4], d_in[5], d_in[6], d_in[7], d_in[8], flag, params0, wt0);
    cvt_params_kernel<<<(PARAM_FLOATS + 255) / 256, 256, 0, stream>>>(
        d_in[9], d_in[10], d_in[11], d_in[12], d_in[13], d_in[14], flag, params1, wt1);

    hipMemsetAsync(bcnt, 0, NBUCK * sizeof(int), stream);
    bin_kernel<<<(E_EDGES + BIN_CH - 1) / BIN_CH, 256, 0, stream>>>(src, dst, bcnt, ebuf);
    bscan_kernel<<<1, 256, 0, stream>>>(bcnt, bbase);
    csr_kernel<<<NBUCK, 256, 0, stream>>>(bcnt, bbase, ebuf, offs, esrc);

    for (int l = 0; l < 2; ++l) {
        float* params = (l == 0) ? params0 : params1;
        unsigned short* wt = (l == 0) ? wt0 : wt1;
        unsigned int* gmax = (l == 0) ? gmax0 : gmax1;
        const void* x = (l == 0) ? features : (const void*)xbuf;
        int mode = (l == 0) ? 0 : 1;

        gemm_mfma_kernel<<<(N_NODES + 63) / 64, 256, 0, stream>>>(
            x, wt, params, flag, mode, hb, el, er, gmax, N_NODES);
        if (l == 0) {
            agg_ln_kernel<false><<<(N_NODES * 64 + 255) / 256, 256, 0, stream>>>(
                offs, esrc, el, er, hb, params, gmax, flag, xbuf, nullptr);
        } else {
            agg_ln_kernel<true><<<(N_NODES * 64 + 255) / 256, 256, 0, stream>>>(
                offs, esrc, el, er, hb, params, gmax, flag, nullptr, d_out);
        }
    }
}